// Round 3
// baseline (18788.629 us; speedup 1.0000x reference)
//
#include <hip/hip_runtime.h>
#include <hip/hip_bf16.h>

typedef __hip_bfloat16 bf16;

#define NB 64
#define NT 512
#define NC 192
#define NHEAD 2
#define NDH 96
#define NLAYER 6
#define NDFF 768
#define NW 4

constexpr int MROWS = NB * NT;            // 32768
constexpr size_t MC = (size_t)MROWS * NC; // 6291456 floats (== B*C*T)

__device__ __forceinline__ float b2f(bf16 x) { return __bfloat162float(x); }

// ---------------- embedding ----------------
__global__ __launch_bounds__(256) void embed_kernel(const int* __restrict__ tok,
                                                    const int* __restrict__ lens,
                                                    const float* __restrict__ emb,
                                                    float* __restrict__ x) {
    int idx = blockIdx.x * 256 + threadIdx.x;
    if (idx >= (int)MC) return;
    int c = idx % NC;
    int m = idx / NC;
    int t = m % NT, b = m / NT;
    float v = emb[tok[m] * NC + c] * 13.856406460551018f; // sqrt(192)
    if (t >= lens[b]) v = 0.f;
    x[idx] = v;
}

// ---------------- generic tiled GEMM, y[m,n] = sum_k A[m,kk]*W[n,kk] + bias[n] ----------------
enum GMode { GM_QKV = 0, GM_OPROJ = 1, GM_CONV1 = 2, GM_CONV2 = 3, GM_PROJ = 4 };

template <int MODE, int N, int K>
__global__ __launch_bounds__(256) void gemm_k(const float* __restrict__ A,
                                              const bf16* __restrict__ Ah,
                                              const float* __restrict__ Wb,
                                              const float* __restrict__ bias,
                                              const int* __restrict__ lens,
                                              float* __restrict__ o0,
                                              float* __restrict__ o1,
                                              float* __restrict__ o2,
                                              bf16* __restrict__ ob) {
    __shared__ float As[16][64];
    __shared__ float Bs[16][64];
    int tid = threadIdx.x;
    int n0 = blockIdx.x * 64;
    int m0 = blockIdx.y * 64; // tile fully inside one batch row (512 % 64 == 0)
    int b = m0 / NT;
    int t0 = m0 % NT;
    int len = lens[b];
    int tx = tid & 15, ty = tid >> 4;
    int lm = tid >> 2;        // 0..63
    int lk = (tid & 3) * 4;   // 0,4,8,12
    float acc[4][4] = {};

    for (int k0 = 0; k0 < K; k0 += 16) {
        // ---- A tile ----
        if constexpr (MODE == GM_CONV1) {
            int t = t0 + lm;
#pragma unroll
            for (int u = 0; u < 4; u++) {
                int kk = k0 + lk + u;
                int c = kk / 3, dk = kk - c * 3;
                int tt = t + dk - 1;
                float v = 0.f;
                if (tt >= 0 && tt < NT && tt < len) v = A[(size_t)(b * NT + tt) * NC + c];
                As[lk + u][lm] = v;
            }
        } else if constexpr (MODE == GM_CONV2) {
            int t = t0 + lm;
#pragma unroll
            for (int u = 0; u < 4; u++) {
                int kk = k0 + lk + u;
                int c = kk / 3, dk = kk - c * 3;
                int tt = t + dk - 1;
                float v = 0.f;
                if (tt >= 0 && tt < NT) v = b2f(Ah[(size_t)(b * NT + tt) * NDFF + c]);
                As[lk + u][lm] = v;
            }
        } else {
            const float4 av = *reinterpret_cast<const float4*>(&A[(size_t)(m0 + lm) * K + k0 + lk]);
            As[lk + 0][lm] = av.x;
            As[lk + 1][lm] = av.y;
            As[lk + 2][lm] = av.z;
            As[lk + 3][lm] = av.w;
        }
        // ---- B tile (weights, f32 row-major (N,K)) ----
        {
            const float4 wv = *reinterpret_cast<const float4*>(&Wb[(size_t)(n0 + lm) * K + k0 + lk]);
            Bs[lk + 0][lm] = wv.x;
            Bs[lk + 1][lm] = wv.y;
            Bs[lk + 2][lm] = wv.z;
            Bs[lk + 3][lm] = wv.w;
        }
        __syncthreads();
#pragma unroll
        for (int k = 0; k < 16; k++) {
            float a0 = As[k][ty * 4 + 0], a1 = As[k][ty * 4 + 1];
            float a2 = As[k][ty * 4 + 2], a3 = As[k][ty * 4 + 3];
            float b0 = Bs[k][tx * 4 + 0], b1 = Bs[k][tx * 4 + 1];
            float b2 = Bs[k][tx * 4 + 2], b3 = Bs[k][tx * 4 + 3];
            acc[0][0] += a0 * b0; acc[0][1] += a0 * b1; acc[0][2] += a0 * b2; acc[0][3] += a0 * b3;
            acc[1][0] += a1 * b0; acc[1][1] += a1 * b1; acc[1][2] += a1 * b2; acc[1][3] += a1 * b3;
            acc[2][0] += a2 * b0; acc[2][1] += a2 * b1; acc[2][2] += a2 * b2; acc[2][3] += a2 * b3;
            acc[3][0] += a3 * b0; acc[3][1] += a3 * b1; acc[3][2] += a3 * b2; acc[3][3] += a3 * b3;
        }
        __syncthreads();
    }

#pragma unroll
    for (int i = 0; i < 4; i++) {
        int m = m0 + ty * 4 + i;
        int t = t0 + ty * 4 + i;
#pragma unroll
        for (int j = 0; j < 4; j++) {
            int n = n0 + tx * 4 + j;
            float v = acc[i][j] + bias[n];
            if constexpr (MODE == GM_QKV) {
                int iw = n / NC;        // 0=q,1=k,2=v  (tiles never straddle: 192 % 64 == 0)
                int cc = n - iw * NC;
                int h = cc / NDH, d = cc - h * NDH;
                float* dst = (iw == 0) ? o0 : ((iw == 1) ? o1 : o2);
                dst[(size_t)((b * NHEAD + h) * NT + t) * NDH + d] = v;
            } else if constexpr (MODE == GM_OPROJ) {
                o0[(size_t)m * NC + n] = v;
            } else if constexpr (MODE == GM_CONV1) {
                v = v > 0.f ? v : 0.f;
                if (t >= len) v = 0.f;
                ob[(size_t)m * NDFF + n] = __float2bfloat16(v);
            } else if constexpr (MODE == GM_CONV2) {
                if (t >= len) v = 0.f;
                o0[(size_t)m * NC + n] = v;
            } else { // GM_PROJ -> transposed f32 store into d_out (m at +MC, logs at +2*MC)
                if (t >= len) v = 0.f;
                int half = n / 192;
                int cc = n - half * 192;
                o0[(size_t)(half + 1) * MC + ((size_t)b * NC + cc) * NT + t] = v;
            }
        }
    }
}

// ---------------- attention: one block per (b,h,t) query row ----------------
__global__ __launch_bounds__(128) void attn_kernel(const float* __restrict__ q,
                                                   const float* __restrict__ k,
                                                   const float* __restrict__ v,
                                                   const float* __restrict__ relk,
                                                   const float* __restrict__ relv,
                                                   const int* __restrict__ lens,
                                                   float* __restrict__ o) {
    __shared__ float sc[NT];
    __shared__ float qs[NDH];
    __shared__ float red[128];
    int row = blockIdx.x;        // (b*NH + h)*T + t
    int t = row & (NT - 1);
    int bh = row >> 9;           // /512
    int b = bh >> 1;             // /NHEAD
    int h = bh & 1;
    int tid = threadIdx.x;
    int len = lens[b];
    bool tok_t = (t < len);
    if (tid < NDH) qs[tid] = q[(size_t)row * NDH + tid] * 0.10206207261596575f; // 1/sqrt(96)
    __syncthreads();

    const float* kb = k + (size_t)bh * NT * NDH;
    const float* vb = v + (size_t)bh * NT * NDH;
    const float4* q4 = reinterpret_cast<const float4*>(qs);

    for (int s = tid; s < NT; s += 128) {
        const float4* kr = reinterpret_cast<const float4*>(kb + (size_t)s * NDH);
        float acc = 0.f;
#pragma unroll
        for (int d4 = 0; d4 < NDH / 4; d4++) {
            float4 qv = q4[d4];
            float4 kv = kr[d4];
            acc += qv.x * kv.x + qv.y * kv.y + qv.z * kv.z + qv.w * kv.w;
        }
        int dd = s - t;
        if (dd >= -NW && dd <= NW) {
            const float* rr = relk + (size_t)(dd + NW) * NDH;
            float a2 = 0.f;
            for (int d = 0; d < NDH; d++) a2 += qs[d] * rr[d];
            acc += a2;
        }
        if (!(tok_t && s < len)) acc -= 10000.f;
        sc[s] = acc;
    }
    __syncthreads();

    float lmx = -1e30f;
    for (int s = tid; s < NT; s += 128) lmx = fmaxf(lmx, sc[s]);
    red[tid] = lmx;
    __syncthreads();
    for (int off = 64; off > 0; off >>= 1) {
        if (tid < off) red[tid] = fmaxf(red[tid], red[tid + off]);
        __syncthreads();
    }
    float mx = red[0];
    __syncthreads();

    float ls = 0.f;
    for (int s = tid; s < NT; s += 128) {
        float e = __expf(sc[s] - mx);
        sc[s] = e;
        ls += e;
    }
    red[tid] = ls;
    __syncthreads();
    for (int off = 64; off > 0; off >>= 1) {
        if (tid < off) red[tid] += red[tid + off];
        __syncthreads();
    }
    float inv_sum = 1.f / red[0];

    for (int d = tid; d < NDH; d += 128) {
        float acc = 0.f;
        for (int s = 0; s < NT; s++) acc += sc[s] * vb[(size_t)s * NDH + d];
#pragma unroll
        for (int dd = -NW; dd <= NW; dd++) {
            int s = t + dd;
            if (s >= 0 && s < NT) acc += sc[s] * relv[(size_t)(dd + NW) * NDH + d];
        }
        o[((size_t)b * NT + t) * NC + h * NDH + d] = acc * inv_sum;
    }
}

// ---------------- x = LN(x + y), one wave per row ----------------
__global__ __launch_bounds__(256) void add_ln_kernel(float* __restrict__ x,
                                                     const float* __restrict__ y,
                                                     const float* __restrict__ g,
                                                     const float* __restrict__ bb) {
    int wid = threadIdx.x >> 6;
    int lane = threadIdx.x & 63;
    int m = blockIdx.x * 4 + wid;
    size_t base = (size_t)m * NC;
    float r[3];
    float s = 0.f;
#pragma unroll
    for (int u = 0; u < 3; u++) {
        int c = lane * 3 + u;
        r[u] = x[base + c] + y[base + c];
        s += r[u];
    }
#pragma unroll
    for (int off = 32; off > 0; off >>= 1) s += __shfl_xor(s, off);
    float mu = s * (1.f / NC);
    float vs = 0.f;
#pragma unroll
    for (int u = 0; u < 3; u++) {
        float d = r[u] - mu;
        vs += d * d;
    }
#pragma unroll
    for (int off = 32; off > 0; off >>= 1) vs += __shfl_xor(vs, off);
    float rs = rsqrtf(vs * (1.f / NC) + 1e-5f);
#pragma unroll
    for (int u = 0; u < 3; u++) {
        int c = lane * 3 + u;
        x[base + c] = (r[u] - mu) * rs * g[c] + bb[c];
    }
}

// ---------------- final x^T store (masked, f32) ----------------
__global__ __launch_bounds__(256) void xpose_kernel(const float* __restrict__ x,
                                                    const int* __restrict__ lens,
                                                    float* __restrict__ out) {
    int idx = blockIdx.x * 256 + threadIdx.x;
    if (idx >= (int)MC) return;
    int t = idx % NT;
    int bc = idx / NT;
    int c = bc % NC;
    int b = bc / NC;
    float v = (t < lens[b]) ? x[((size_t)b * NT + t) * NC + c] : 0.f;
    out[idx] = v;
}

__global__ __launch_bounds__(256) void mask_kernel(const int* __restrict__ lens, float* __restrict__ out) {
    int idx = blockIdx.x * 256 + threadIdx.x;
    if (idx >= NB * NT) return;
    int t = idx % NT;
    int b = idx / NT;
    out[idx] = (t < lens[b]) ? 1.f : 0.f;
}

extern "C" void kernel_launch(void* const* d_in, const int* in_sizes, int n_in,
                              void* d_out, int out_size, void* d_ws, size_t ws_size,
                              hipStream_t stream) {
    (void)in_sizes; (void)n_in; (void)out_size; (void)ws_size;
    const int* tok = (const int*)d_in[0];
    const int* lens = (const int*)d_in[1];
    const float* emb = (const float*)d_in[2];
    const float* wqkv = (const float*)d_in[3];
    const float* bqkv = (const float*)d_in[4];
    const float* wo = (const float*)d_in[5];
    const float* bo = (const float*)d_in[6];
    const float* relk = (const float*)d_in[7];
    const float* relv = (const float*)d_in[8];
    const float* ln1g = (const float*)d_in[9];
    const float* ln1b = (const float*)d_in[10];
    const float* ln2g = (const float*)d_in[11];
    const float* ln2b = (const float*)d_in[12];
    const float* fw1 = (const float*)d_in[13];
    const float* fb1 = (const float*)d_in[14];
    const float* fw2 = (const float*)d_in[15];
    const float* fb2 = (const float*)d_in[16];
    const float* pw = (const float*)d_in[17];
    const float* pb = (const float*)d_in[18];
    float* out = (float*)d_out;

    float* ws = (float*)d_ws;
    float* xB = ws;
    float* qB = ws + MC;
    float* kB = ws + 2 * MC;
    float* vB = ws + 3 * MC;
    float* oB = ws + 4 * MC;
    float* yB = qB;            // alias: q free after attention
    bf16* hB = (bf16*)kB;      // alias: k+v region (2*MC*4 bytes == M*DFF*2 bytes)

    embed_kernel<<<(int)((MC + 255) / 256), 256, 0, stream>>>(tok, lens, emb, xB);

    for (int l = 0; l < NLAYER; l++) {
        gemm_k<GM_QKV, 576, 192><<<dim3(9, 512), 256, 0, stream>>>(
            xB, nullptr, wqkv + (size_t)l * 3 * NC * NC, bqkv + (size_t)l * 3 * NC, lens,
            qB, kB, vB, nullptr);
        attn_kernel<<<NB * NHEAD * NT, 128, 0, stream>>>(
            qB, kB, vB, relk + (size_t)l * (2 * NW + 1) * NDH,
            relv + (size_t)l * (2 * NW + 1) * NDH, lens, oB);
        gemm_k<GM_OPROJ, 192, 192><<<dim3(3, 512), 256, 0, stream>>>(
            oB, nullptr, wo + (size_t)l * NC * NC, bo + (size_t)l * NC, lens,
            yB, nullptr, nullptr, nullptr);
        add_ln_kernel<<<MROWS / 4, 256, 0, stream>>>(xB, yB, ln1g + (size_t)l * NC, ln1b + (size_t)l * NC);
        gemm_k<GM_CONV1, 768, 576><<<dim3(12, 512), 256, 0, stream>>>(
            xB, nullptr, fw1 + (size_t)l * NDFF * NC * 3, fb1 + (size_t)l * NDFF, lens,
            nullptr, nullptr, nullptr, hB);
        gemm_k<GM_CONV2, 192, 2304><<<dim3(3, 512), 256, 0, stream>>>(
            nullptr, hB, fw2 + (size_t)l * NC * NDFF * 3, fb2 + (size_t)l * NC, lens,
            yB, nullptr, nullptr, nullptr);
        add_ln_kernel<<<MROWS / 4, 256, 0, stream>>>(xB, yB, ln2g + (size_t)l * NC, ln2b + (size_t)l * NC);
    }

    gemm_k<GM_PROJ, 384, 192><<<dim3(6, 512), 256, 0, stream>>>(
        xB, nullptr, pw, pb, lens, out, nullptr, nullptr, nullptr);
    xpose_kernel<<<(int)((MC + 255) / 256), 256, 0, stream>>>(xB, lens, out);
    mask_kernel<<<(NB * NT + 255) / 256, 256, 0, stream>>>(lens, out + 3 * MC);
}

// Round 4
// 8227.451 us; speedup vs baseline: 2.2837x; 2.2837x over previous
//
#include <hip/hip_runtime.h>
#include <hip/hip_bf16.h>

typedef __hip_bfloat16 bf16;
typedef __attribute__((ext_vector_type(8))) short short8;
typedef __attribute__((ext_vector_type(4))) float f32x4;

#define NB 64
#define NT 512
#define NC 192
#define NHEAD 2
#define NDH 96
#define NLAYER 6
#define NDFF 768
#define NW 4

constexpr int MROWS = NB * NT;            // 32768
constexpr size_t MC = (size_t)MROWS * NC; // 6291456 floats

__device__ __forceinline__ float b2f(bf16 x) { return __bfloat162float(x); }
__device__ __forceinline__ float us2f(unsigned short x) { return __uint_as_float((unsigned)x << 16); }
__device__ __forceinline__ unsigned short f2b(float f) {
    bf16 h = __float2bfloat16(f);
    return *reinterpret_cast<unsigned short*>(&h);
}

// ---------------- embedding ----------------
__global__ __launch_bounds__(256) void embed_kernel(const int* __restrict__ tok,
                                                    const int* __restrict__ lens,
                                                    const float* __restrict__ emb,
                                                    float* __restrict__ x) {
    int idx = blockIdx.x * 256 + threadIdx.x;
    if (idx >= (int)MC) return;
    int c = idx % NC;
    int m = idx / NC;
    int t = m % NT, b = m / NT;
    float v = emb[tok[m] * NC + c] * 13.856406460551018f; // sqrt(192)
    if (t >= lens[b]) v = 0.f;
    x[idx] = v;
}

// ---------------- generic tiled GEMM (f32 VALU) ----------------
enum GMode { GM_QKV = 0, GM_OPROJ = 1, GM_CONV1 = 2, GM_CONV2 = 3, GM_PROJ = 4 };

template <int MODE, int N, int K>
__global__ __launch_bounds__(256) void gemm_k(const float* __restrict__ A,
                                              const bf16* __restrict__ Ah,
                                              const float* __restrict__ Wb,
                                              const float* __restrict__ bias,
                                              const int* __restrict__ lens,
                                              float* __restrict__ o0,
                                              float* __restrict__ o1,
                                              float* __restrict__ o2,
                                              bf16* __restrict__ ob) {
    __shared__ float As[16][64];
    __shared__ float Bs[16][64];
    int tid = threadIdx.x;
    int n0 = blockIdx.x * 64;
    int m0 = blockIdx.y * 64;
    int b = m0 / NT;
    int t0 = m0 % NT;
    int len = lens[b];
    int tx = tid & 15, ty = tid >> 4;
    int lm = tid >> 2;
    int lk = (tid & 3) * 4;
    float acc[4][4] = {};

    for (int k0 = 0; k0 < K; k0 += 16) {
        if constexpr (MODE == GM_CONV1) {
            int t = t0 + lm;
#pragma unroll
            for (int u = 0; u < 4; u++) {
                int kk = k0 + lk + u;
                int c = kk / 3, dk = kk - c * 3;
                int tt = t + dk - 1;
                float v = 0.f;
                if (tt >= 0 && tt < NT && tt < len) v = A[(size_t)(b * NT + tt) * NC + c];
                As[lk + u][lm] = v;
            }
        } else if constexpr (MODE == GM_CONV2) {
            int t = t0 + lm;
#pragma unroll
            for (int u = 0; u < 4; u++) {
                int kk = k0 + lk + u;
                int c = kk / 3, dk = kk - c * 3;
                int tt = t + dk - 1;
                float v = 0.f;
                if (tt >= 0 && tt < NT) v = b2f(Ah[(size_t)(b * NT + tt) * NDFF + c]);
                As[lk + u][lm] = v;
            }
        } else {
            const float4 av = *reinterpret_cast<const float4*>(&A[(size_t)(m0 + lm) * K + k0 + lk]);
            As[lk + 0][lm] = av.x;
            As[lk + 1][lm] = av.y;
            As[lk + 2][lm] = av.z;
            As[lk + 3][lm] = av.w;
        }
        {
            const float4 wv = *reinterpret_cast<const float4*>(&Wb[(size_t)(n0 + lm) * K + k0 + lk]);
            Bs[lk + 0][lm] = wv.x;
            Bs[lk + 1][lm] = wv.y;
            Bs[lk + 2][lm] = wv.z;
            Bs[lk + 3][lm] = wv.w;
        }
        __syncthreads();
#pragma unroll
        for (int k = 0; k < 16; k++) {
            float a0 = As[k][ty * 4 + 0], a1 = As[k][ty * 4 + 1];
            float a2 = As[k][ty * 4 + 2], a3 = As[k][ty * 4 + 3];
            float b0 = Bs[k][tx * 4 + 0], b1 = Bs[k][tx * 4 + 1];
            float b2 = Bs[k][tx * 4 + 2], b3 = Bs[k][tx * 4 + 3];
            acc[0][0] += a0 * b0; acc[0][1] += a0 * b1; acc[0][2] += a0 * b2; acc[0][3] += a0 * b3;
            acc[1][0] += a1 * b0; acc[1][1] += a1 * b1; acc[1][2] += a1 * b2; acc[1][3] += a1 * b3;
            acc[2][0] += a2 * b0; acc[2][1] += a2 * b1; acc[2][2] += a2 * b2; acc[2][3] += a2 * b3;
            acc[3][0] += a3 * b0; acc[3][1] += a3 * b1; acc[3][2] += a3 * b2; acc[3][3] += a3 * b3;
        }
        __syncthreads();
    }

#pragma unroll
    for (int i = 0; i < 4; i++) {
        int m = m0 + ty * 4 + i;
        int t = t0 + ty * 4 + i;
#pragma unroll
        for (int j = 0; j < 4; j++) {
            int n = n0 + tx * 4 + j;
            float v = acc[i][j] + bias[n];
            if constexpr (MODE == GM_QKV) {
                int iw = n / NC;
                int cc = n - iw * NC;
                int h = cc / NDH, d = cc - h * NDH;
                float* dst = (iw == 0) ? o0 : ((iw == 1) ? o1 : o2);
                dst[(size_t)((b * NHEAD + h) * NT + t) * NDH + d] = v;
            } else if constexpr (MODE == GM_OPROJ) {
                o0[(size_t)m * NC + n] = v;
            } else if constexpr (MODE == GM_CONV1) {
                v = v > 0.f ? v : 0.f;
                if (t >= len) v = 0.f;
                ob[(size_t)m * NDFF + n] = __float2bfloat16(v);
            } else if constexpr (MODE == GM_CONV2) {
                if (t >= len) v = 0.f;
                o0[(size_t)m * NC + n] = v;
            } else { // GM_PROJ -> transposed f32 store
                if (t >= len) v = 0.f;
                int half = n / 192;
                int cc = n - half * 192;
                o0[(size_t)(half + 1) * MC + ((size_t)b * NC + cc) * NT + t] = v;
            }
        }
    }
}

// ---------------- MFMA flash attention ----------------
// grid (8, B*NH), block 256 (4 waves). Wave w owns q-rows q0+w*16..+15.
// mfma_f32_16x16x32_bf16: A lane: row=l&15, k=(l>>4)*8+i ; B lane: col=l&15, k=(l>>4)*8+i
// C/D lane: col=l&15, row=(l>>4)*4+reg   [measured m89/m91]
#define KP 104   // Qt/Kt padded row (bf16): 208B, 16B-aligned rows, 2-way-bank free
#define VP 72    // Vt padded row: 144B
#define PP 72    // Pt padded row

__global__ __launch_bounds__(256) void attn_mfma(const float* __restrict__ q,
                                                 const float* __restrict__ k,
                                                 const float* __restrict__ v,
                                                 const float* __restrict__ relk,
                                                 const float* __restrict__ relv,
                                                 const int* __restrict__ lens,
                                                 float* __restrict__ o) {
    __shared__ unsigned short Qt[64 * KP];
    __shared__ unsigned short Kt[64 * KP];
    __shared__ unsigned short Vt[96 * VP];
    __shared__ unsigned short Pt[4][16 * PP];
    __shared__ float Rt[64][9];
    __shared__ float rvs[9][96];

    const int qt = blockIdx.x;
    const int bh = blockIdx.y;
    const int b = bh >> 1, h = bh & 1;
    const int q0 = qt * 64;
    const int tid = threadIdx.x;
    const int w = tid >> 6, lane = tid & 63;
    const int g = lane >> 4, li = lane & 15;
    const int len = lens[b];
    const float scale = 0.10206207261596575f; // 1/sqrt(96)

    const float* qg = q + (size_t)bh * NT * NDH;
    const float* kg = k + (size_t)bh * NT * NDH;
    const float* vg = v + (size_t)bh * NT * NDH;

    // stage Q (scaled) and rel_v table
    for (int idx = tid; idx < 64 * NDH; idx += 256) {
        int r = idx / NDH, d = idx - r * NDH;
        Qt[r * KP + d] = f2b(qg[(size_t)(q0 + r) * NDH + d] * scale);
    }
    for (int idx = tid; idx < 9 * 96; idx += 256) rvs[idx / 96][idx % 96] = relv[idx];
    __syncthreads();
    // rel-K table: Rt[r][dd] = dot(q_scaled[r], rel_k[dd])
    for (int idx = tid; idx < 64 * 9; idx += 256) {
        int r = idx / 9, dd = idx - r * 9;
        float s = 0.f;
        for (int d = 0; d < 96; d++) s += us2f(Qt[r * KP + d]) * relk[dd * 96 + d];
        Rt[r][dd] = s;
    }

    // Q fragments (per wave, rows w*16+li)
    short8 qf[3];
#pragma unroll
    for (int kk = 0; kk < 3; kk++)
        qf[kk] = *reinterpret_cast<const short8*>(&Qt[(w * 16 + li) * KP + kk * 32 + g * 8]);

    float m_run[4], l_run[4];
    f32x4 Oa[6];
#pragma unroll
    for (int rr = 0; rr < 4; rr++) { m_run[rr] = -1e30f; l_run[rr] = 0.f; }
#pragma unroll
    for (int ds = 0; ds < 6; ds++) Oa[ds] = (f32x4){0.f, 0.f, 0.f, 0.f};

    for (int s0 = 0; s0 < NT; s0 += 64) {
        __syncthreads(); // previous tile's K/V no longer in use
        for (int idx = tid; idx < 64 * 96; idx += 256) {
            int ss = idx / 96, d = idx - ss * 96;
            float kvf = kg[(size_t)(s0 + ss) * 96 + d];
            float vvf = vg[(size_t)(s0 + ss) * 96 + d];
            Kt[ss * KP + d] = f2b(kvf);
            Vt[d * VP + ss] = f2b(vvf);
        }
        __syncthreads();

        // S = Q·K^T (16x64 per wave)
        f32x4 acc[4];
#pragma unroll
        for (int sub = 0; sub < 4; sub++) acc[sub] = (f32x4){0.f, 0.f, 0.f, 0.f};
#pragma unroll
        for (int kk = 0; kk < 3; kk++) {
#pragma unroll
            for (int sub = 0; sub < 4; sub++) {
                short8 bfr = *reinterpret_cast<const short8*>(&Kt[(sub * 16 + li) * KP + kk * 32 + g * 8]);
                acc[sub] = __builtin_amdgcn_mfma_f32_16x16x32_bf16(qf[kk], bfr, acc[sub], 0, 0, 0);
            }
        }

        // rel-K band + mask + row max
        float rmax[4];
#pragma unroll
        for (int rr = 0; rr < 4; rr++) rmax[rr] = -1e30f;
#pragma unroll
        for (int sub = 0; sub < 4; sub++) {
#pragma unroll
            for (int rr = 0; rr < 4; rr++) {
                int scol = s0 + sub * 16 + li;
                int qrow = q0 + w * 16 + 4 * g + rr;
                float val = acc[sub][rr];
                int dd = scol - qrow;
                if (dd >= -NW && dd <= NW) val += Rt[w * 16 + 4 * g + rr][dd + NW];
                if (scol >= len || qrow >= len) val -= 10000.f;
                acc[sub][rr] = val;
                rmax[rr] = fmaxf(rmax[rr], val);
            }
        }
#pragma unroll
        for (int off = 1; off < 16; off <<= 1) {
#pragma unroll
            for (int rr = 0; rr < 4; rr++) rmax[rr] = fmaxf(rmax[rr], __shfl_xor(rmax[rr], off));
        }

        // online softmax update
        float sc[4];
#pragma unroll
        for (int rr = 0; rr < 4; rr++) {
            float mn = fmaxf(m_run[rr], rmax[rr]);
            sc[rr] = __expf(m_run[rr] - mn);
            m_run[rr] = mn;
        }
        float rsum[4] = {0.f, 0.f, 0.f, 0.f};
#pragma unroll
        for (int sub = 0; sub < 4; sub++) {
#pragma unroll
            for (int rr = 0; rr < 4; rr++) {
                float p = __expf(acc[sub][rr] - m_run[rr]);
                acc[sub][rr] = p;
                rsum[rr] += p;
            }
        }
#pragma unroll
        for (int off = 1; off < 16; off <<= 1) {
#pragma unroll
            for (int rr = 0; rr < 4; rr++) rsum[rr] += __shfl_xor(rsum[rr], off);
        }
#pragma unroll
        for (int rr = 0; rr < 4; rr++) l_run[rr] = l_run[rr] * sc[rr] + rsum[rr];
#pragma unroll
        for (int ds = 0; ds < 6; ds++) {
#pragma unroll
            for (int rr = 0; rr < 4; rr++) Oa[ds][rr] *= sc[rr];
        }

        // P -> LDS (per-wave private region; same-wave RAW handled by compiler waitcnt)
#pragma unroll
        for (int sub = 0; sub < 4; sub++) {
#pragma unroll
            for (int rr = 0; rr < 4; rr++)
                Pt[w][(4 * g + rr) * PP + sub * 16 + li] = f2b(acc[sub][rr]);
        }

        // O += P·V
#pragma unroll
        for (int kk = 0; kk < 2; kk++) {
            short8 pa = *reinterpret_cast<const short8*>(&Pt[w][li * PP + kk * 32 + g * 8]);
#pragma unroll
            for (int ds = 0; ds < 6; ds++) {
                short8 bv = *reinterpret_cast<const short8*>(&Vt[(ds * 16 + li) * VP + kk * 32 + g * 8]);
                Oa[ds] = __builtin_amdgcn_mfma_f32_16x16x32_bf16(pa, bv, Oa[ds], 0, 0, 0);
            }
        }

        // rel-V band contribution (same rescaling as Oa)
#pragma unroll
        for (int rr = 0; rr < 4; rr++) {
            int rl = w * 16 + 4 * g + rr;
            int qrow = q0 + rl;
#pragma unroll
            for (int dd = -NW; dd <= NW; dd++) {
                int s = qrow + dd;
                if (s >= s0 && s < s0 + 64) {
                    float p = us2f(Pt[w][(4 * g + rr) * PP + (s - s0)]);
#pragma unroll
                    for (int ds = 0; ds < 6; ds++)
                        Oa[ds][rr] += p * rvs[dd + NW][ds * 16 + li];
                }
            }
        }
    }

    float invl[4];
#pragma unroll
    for (int rr = 0; rr < 4; rr++) invl[rr] = 1.f / l_run[rr];
#pragma unroll
    for (int ds = 0; ds < 6; ds++) {
#pragma unroll
        for (int rr = 0; rr < 4; rr++) {
            int qrow = q0 + w * 16 + 4 * g + rr;
            o[((size_t)(b * NT + qrow)) * NC + h * 96 + ds * 16 + li] = Oa[ds][rr] * invl[rr];
        }
    }
}

// ---------------- x = LN(x + y), one wave per row ----------------
__global__ __launch_bounds__(256) void add_ln_kernel(float* __restrict__ x,
                                                     const float* __restrict__ y,
                                                     const float* __restrict__ g,
                                                     const float* __restrict__ bb) {
    int wid = threadIdx.x >> 6;
    int lane = threadIdx.x & 63;
    int m = blockIdx.x * 4 + wid;
    size_t base = (size_t)m * NC;
    float r[3];
    float s = 0.f;
#pragma unroll
    for (int u = 0; u < 3; u++) {
        int c = lane * 3 + u;
        r[u] = x[base + c] + y[base + c];
        s += r[u];
    }
#pragma unroll
    for (int off = 32; off > 0; off >>= 1) s += __shfl_xor(s, off);
    float mu = s * (1.f / NC);
    float vs = 0.f;
#pragma unroll
    for (int u = 0; u < 3; u++) {
        float d = r[u] - mu;
        vs += d * d;
    }
#pragma unroll
    for (int off = 32; off > 0; off >>= 1) vs += __shfl_xor(vs, off);
    float rs = rsqrtf(vs * (1.f / NC) + 1e-5f);
#pragma unroll
    for (int u = 0; u < 3; u++) {
        int c = lane * 3 + u;
        x[base + c] = (r[u] - mu) * rs * g[c] + bb[c];
    }
}

// ---------------- final x^T store (masked, f32) ----------------
__global__ __launch_bounds__(256) void xpose_kernel(const float* __restrict__ x,
                                                    const int* __restrict__ lens,
                                                    float* __restrict__ out) {
    int idx = blockIdx.x * 256 + threadIdx.x;
    if (idx >= (int)MC) return;
    int t = idx % NT;
    int bc = idx / NT;
    int c = bc % NC;
    int b = bc / NC;
    float v = (t < lens[b]) ? x[((size_t)b * NT + t) * NC + c] : 0.f;
    out[idx] = v;
}

__global__ __launch_bounds__(256) void mask_kernel(const int* __restrict__ lens, float* __restrict__ out) {
    int idx = blockIdx.x * 256 + threadIdx.x;
    if (idx >= NB * NT) return;
    int t = idx % NT;
    int b = idx / NT;
    out[idx] = (t < lens[b]) ? 1.f : 0.f;
}

extern "C" void kernel_launch(void* const* d_in, const int* in_sizes, int n_in,
                              void* d_out, int out_size, void* d_ws, size_t ws_size,
                              hipStream_t stream) {
    (void)in_sizes; (void)n_in; (void)out_size; (void)ws_size;
    const int* tok = (const int*)d_in[0];
    const int* lens = (const int*)d_in[1];
    const float* emb = (const float*)d_in[2];
    const float* wqkv = (const float*)d_in[3];
    const float* bqkv = (const float*)d_in[4];
    const float* wo = (const float*)d_in[5];
    const float* bo = (const float*)d_in[6];
    const float* relk = (const float*)d_in[7];
    const float* relv = (const float*)d_in[8];
    const float* ln1g = (const float*)d_in[9];
    const float* ln1b = (const float*)d_in[10];
    const float* ln2g = (const float*)d_in[11];
    const float* ln2b = (const float*)d_in[12];
    const float* fw1 = (const float*)d_in[13];
    const float* fb1 = (const float*)d_in[14];
    const float* fw2 = (const float*)d_in[15];
    const float* fb2 = (const float*)d_in[16];
    const float* pw = (const float*)d_in[17];
    const float* pb = (const float*)d_in[18];
    float* out = (float*)d_out;

    float* ws = (float*)d_ws;
    float* xB = ws;
    float* qB = ws + MC;
    float* kB = ws + 2 * MC;
    float* vB = ws + 3 * MC;
    float* oB = ws + 4 * MC;
    float* yB = qB;            // alias: q free after attention
    bf16* hB = (bf16*)kB;      // alias: k+v region

    embed_kernel<<<(int)((MC + 255) / 256), 256, 0, stream>>>(tok, lens, emb, xB);

    for (int l = 0; l < NLAYER; l++) {
        gemm_k<GM_QKV, 576, 192><<<dim3(9, 512), 256, 0, stream>>>(
            xB, nullptr, wqkv + (size_t)l * 3 * NC * NC, bqkv + (size_t)l * 3 * NC, lens,
            qB, kB, vB, nullptr);
        attn_mfma<<<dim3(8, NB * NHEAD), 256, 0, stream>>>(
            qB, kB, vB, relk + (size_t)l * (2 * NW + 1) * NDH,
            relv + (size_t)l * (2 * NW + 1) * NDH, lens, oB);
        gemm_k<GM_OPROJ, 192, 192><<<dim3(3, 512), 256, 0, stream>>>(
            oB, nullptr, wo + (size_t)l * NC * NC, bo + (size_t)l * NC, lens,
            yB, nullptr, nullptr, nullptr);
        add_ln_kernel<<<MROWS / 4, 256, 0, stream>>>(xB, yB, ln1g + (size_t)l * NC, ln1b + (size_t)l * NC);
        gemm_k<GM_CONV1, 768, 576><<<dim3(12, 512), 256, 0, stream>>>(
            xB, nullptr, fw1 + (size_t)l * NDFF * NC * 3, fb1 + (size_t)l * NDFF, lens,
            nullptr, nullptr, nullptr, hB);
        gemm_k<GM_CONV2, 192, 2304><<<dim3(3, 512), 256, 0, stream>>>(
            nullptr, hB, fw2 + (size_t)l * NC * NDFF * 3, fb2 + (size_t)l * NC, lens,
            yB, nullptr, nullptr, nullptr);
        add_ln_kernel<<<MROWS / 4, 256, 0, stream>>>(xB, yB, ln2g + (size_t)l * NC, ln2b + (size_t)l * NC);
    }

    gemm_k<GM_PROJ, 384, 192><<<dim3(6, 512), 256, 0, stream>>>(
        xB, nullptr, pw, pb, lens, out, nullptr, nullptr, nullptr);
    xpose_kernel<<<(int)((MC + 255) / 256), 256, 0, stream>>>(xB, lens, out);
    mask_kernel<<<(NB * NT + 255) / 256, 256, 0, stream>>>(lens, out + 3 * MC);
}

// Round 5
// 2307.493 us; speedup vs baseline: 8.1424x; 3.5655x over previous
//
#include <hip/hip_runtime.h>
#include <hip/hip_bf16.h>

typedef __hip_bfloat16 bf16;
typedef __attribute__((ext_vector_type(8))) short short8;
typedef __attribute__((ext_vector_type(4))) float f32x4;

#define NB 64
#define NT 512
#define NC 192
#define NHEAD 2
#define NDH 96
#define NLAYER 6
#define NDFF 768
#define NW 4

constexpr int MROWS = NB * NT;            // 32768
constexpr size_t MC = (size_t)MROWS * NC; // 6291456
constexpr size_t MCB = MC * 4;            // bytes of one f32 [M][C] buffer

__device__ __forceinline__ float us2f(unsigned short x) { return __uint_as_float((unsigned)x << 16); }
__device__ __forceinline__ unsigned short f2b(float f) {
    bf16 h = __float2bfloat16(f);
    return *reinterpret_cast<unsigned short*>(&h);
}

// ---------------- weight conversion ----------------
__global__ __launch_bounds__(256) void cvt_plain(const float* __restrict__ s, bf16* __restrict__ d, int n) {
    int i = blockIdx.x * 256 + threadIdx.x;
    if (i < n) d[i] = __float2bfloat16(s[i]);
}
// [L][N][C][3] f32 -> [L][3][N][C] bf16
__global__ __launch_bounds__(256) void cvt_conv(const float* __restrict__ s, bf16* __restrict__ d,
                                                int L, int N, int C) {
    int i = blockIdx.x * 256 + threadIdx.x;
    if (i >= L * N * C * 3) return;
    int dk = i % 3;
    int rest = i / 3;
    int c = rest % C;
    int rest2 = rest / C;
    int n = rest2 % N;
    int l = rest2 / N;
    d[(((size_t)l * 3 + dk) * N + n) * C + c] = __float2bfloat16(s[i]);
}

// ---------------- embedding ----------------
__global__ __launch_bounds__(256) void embed_kernel(const int* __restrict__ tok,
                                                    const int* __restrict__ lens,
                                                    const float* __restrict__ emb,
                                                    float* __restrict__ x,
                                                    bf16* __restrict__ xb) {
    int idx = blockIdx.x * 256 + threadIdx.x;
    if (idx >= (int)MC) return;
    int c = idx % NC;
    int m = idx / NC;
    int t = m % NT, b = m / NT;
    float v = emb[tok[m] * NC + c] * 13.856406460551018f; // sqrt(192)
    if (t >= lens[b]) v = 0.f;
    x[idx] = v;
    xb[idx] = __float2bfloat16(v);
}

// ---------------- MFMA GEMM: y[m,n] = sum_taps sum_k A[t+dk-1,k]*W[dk,n,k] + bias[n] ----------------
enum GMode { GM_QKV = 0, GM_OPROJ = 1, GM_CONV1 = 2, GM_CONV2 = 3, GM_PROJ = 4 };

template <int MODE, int NTOT, int KC, int TAPS>
__global__ __launch_bounds__(256) void gemm_mfma(const bf16* __restrict__ A,
                                                 const bf16* __restrict__ W,
                                                 const float* __restrict__ bias,
                                                 const int* __restrict__ lens,
                                                 float* __restrict__ of,
                                                 bf16* __restrict__ ob1,
                                                 bf16* __restrict__ ob2,
                                                 bf16* __restrict__ ob3) {
    __shared__ unsigned short As[128 * 40]; // rows padded to 40 shorts (80B): 2-way bank alias only
    __shared__ unsigned short Bs[64 * 40];
    const int tid = threadIdx.x;
    const int w = tid >> 6, lane = tid & 63;
    const int g = lane >> 4, li = lane & 15;
    const int n0 = blockIdx.x * 64;
    const int m0 = blockIdx.y * 128; // 128 | 512 -> tile within one batch
    const int b = m0 >> 9;
    const int t0 = m0 & 511;
    const int len = lens[b];

    f32x4 acc[2][4];
#pragma unroll
    for (int a = 0; a < 2; a++)
#pragma unroll
        for (int s = 0; s < 4; s++) acc[a][s] = (f32x4){0.f, 0.f, 0.f, 0.f};

    const int ar = tid >> 1;          // 0..127
    const int ac = (tid & 1) * 16;    // 0/16
    const int br = tid >> 2;          // 0..63
    const int bc = (tid & 3) * 8;
    const unsigned short* Au = (const unsigned short*)A;
    const unsigned short* Wu = (const unsigned short*)W;

#pragma unroll 1
    for (int dk = 0; dk < TAPS; dk++) {
#pragma unroll 1
        for (int k0 = 0; k0 < KC; k0 += 32) {
            __syncthreads();
            { // stage A (bf16 global -> LDS)
                int t = t0 + ar + (TAPS == 3 ? (dk - 1) : 0);
                bool valid = (t >= 0) && (t < NT);
                if constexpr (MODE == GM_CONV1) valid = valid && (t < len);
                if (valid) {
                    const unsigned short* src = Au + ((size_t)(b * NT + t) * KC + k0 + ac);
                    *(short8*)&As[ar * 40 + ac] = *(const short8*)src;
                    *(short8*)&As[ar * 40 + ac + 8] = *(const short8*)(src + 8);
                } else {
                    short8 z{};
                    *(short8*)&As[ar * 40 + ac] = z;
                    *(short8*)&As[ar * 40 + ac + 8] = z;
                }
            }
            { // stage B
                const unsigned short* src = Wu + ((size_t)(dk * NTOT + n0 + br) * KC + k0 + bc);
                *(short8*)&Bs[br * 40 + bc] = *(const short8*)src;
            }
            __syncthreads();
            short8 af0 = *(const short8*)&As[(w * 32 + li) * 40 + g * 8];
            short8 af1 = *(const short8*)&As[(w * 32 + 16 + li) * 40 + g * 8];
#pragma unroll
            for (int sub = 0; sub < 4; sub++) {
                short8 bfr = *(const short8*)&Bs[(sub * 16 + li) * 40 + g * 8];
                acc[0][sub] = __builtin_amdgcn_mfma_f32_16x16x32_bf16(af0, bfr, acc[0][sub], 0, 0, 0);
                acc[1][sub] = __builtin_amdgcn_mfma_f32_16x16x32_bf16(af1, bfr, acc[1][sub], 0, 0, 0);
            }
        }
    }

    // epilogue: m = m0 + w*32 + a*16 + g*4 + rr ; n = n0 + sub*16 + li
#pragma unroll
    for (int sub = 0; sub < 4; sub++) {
        int n = n0 + sub * 16 + li;
        float bv = bias[n];
#pragma unroll
        for (int a = 0; a < 2; a++) {
#pragma unroll
            for (int rr = 0; rr < 4; rr++) {
                int t = t0 + w * 32 + a * 16 + g * 4 + rr;
                size_t m = (size_t)(b * NT + t);
                float vv = acc[a][sub][rr] + bv;
                if constexpr (MODE == GM_QKV) {
                    int iw = n / NC;
                    int cc = n - iw * NC;
                    int hh = cc >= NDH ? 1 : 0;
                    int d = cc - hh * NDH;
                    bf16* dst = (iw == 0) ? ob1 : ((iw == 1) ? ob2 : ob3);
                    dst[((size_t)(b * NHEAD + hh) * NT + t) * NDH + d] = __float2bfloat16(vv);
                } else if constexpr (MODE == GM_OPROJ) {
                    of[m * NC + n] = vv;
                } else if constexpr (MODE == GM_CONV1) {
                    vv = vv > 0.f ? vv : 0.f;
                    if (t >= len) vv = 0.f;
                    ob1[m * NDFF + n] = __float2bfloat16(vv);
                } else if constexpr (MODE == GM_CONV2) {
                    if (t >= len) vv = 0.f;
                    of[m * NC + n] = vv;
                } else { // GM_PROJ
                    if (t >= len) vv = 0.f;
                    int half = n >= 192 ? 1 : 0;
                    int cc = n - half * 192;
                    of[(size_t)(half + 1) * MC + ((size_t)b * NC + cc) * NT + t] = vv;
                }
            }
        }
    }
}

// ---------------- MFMA flash attention (bf16 in/out) ----------------
#define KP 104
#define VP 72
#define PP 72

__global__ __launch_bounds__(256) void attn_mfma(const bf16* __restrict__ q,
                                                 const bf16* __restrict__ k,
                                                 const bf16* __restrict__ v,
                                                 const float* __restrict__ relk,
                                                 const float* __restrict__ relv,
                                                 const int* __restrict__ lens,
                                                 bf16* __restrict__ o) {
    __shared__ unsigned short Qt[64 * KP];
    __shared__ unsigned short Kt[64 * KP];
    __shared__ unsigned short Vt[96 * VP];
    __shared__ unsigned short Pt[4][16 * PP];
    __shared__ float Rt[64][9];
    __shared__ float rvs[9][96];

    const int qt = blockIdx.x;
    const int bh = blockIdx.y;
    const int b = bh >> 1, h = bh & 1;
    const int q0 = qt * 64;
    const int tid = threadIdx.x;
    const int w = tid >> 6, lane = tid & 63;
    const int g = lane >> 4, li = lane & 15;
    const int len = lens[b];
    const float scale = 0.10206207261596575f; // 1/sqrt(96)

    const unsigned short* qg = (const unsigned short*)q + (size_t)bh * NT * NDH;
    const unsigned short* kg = (const unsigned short*)k + (size_t)bh * NT * NDH;
    const unsigned short* vg = (const unsigned short*)v + (size_t)bh * NT * NDH;

    // stage Q (unscaled) + rel_v
    for (int idx = tid; idx < 64 * 12; idx += 256) {
        int r = idx / 12, seg = idx - r * 12;
        *(short8*)&Qt[r * KP + seg * 8] = *(const short8*)(qg + (size_t)(q0 + r) * NDH + seg * 8);
    }
    for (int idx = tid; idx < 9 * 96; idx += 256) rvs[idx / 96][idx % 96] = relv[idx];
    __syncthreads();
    // rel-K table (unscaled q): Rt[r][dd] = dot(q[r], rel_k[dd])
    for (int idx = tid; idx < 64 * 9; idx += 256) {
        int r = idx / 9, dd = idx - r * 9;
        float s = 0.f;
        for (int d = 0; d < 96; d++) s += us2f(Qt[r * KP + d]) * relk[dd * 96 + d];
        Rt[r][dd] = s;
    }

    short8 qf[3];
#pragma unroll
    for (int kk = 0; kk < 3; kk++)
        qf[kk] = *reinterpret_cast<const short8*>(&Qt[(w * 16 + li) * KP + kk * 32 + g * 8]);

    float m_run[4], l_run[4];
    f32x4 Oa[6];
#pragma unroll
    for (int rr = 0; rr < 4; rr++) { m_run[rr] = -1e30f; l_run[rr] = 0.f; }
#pragma unroll
    for (int ds = 0; ds < 6; ds++) Oa[ds] = (f32x4){0.f, 0.f, 0.f, 0.f};

    for (int s0 = 0; s0 < NT; s0 += 64) {
        __syncthreads();
        for (int idx = tid; idx < 64 * 12; idx += 256) {
            int ss = idx / 12, seg = idx - ss * 12;
            *(short8*)&Kt[ss * KP + seg * 8] = *(const short8*)(kg + (size_t)(s0 + ss) * NDH + seg * 8);
        }
        for (int idx = tid; idx < 64 * 96; idx += 256) {
            int ss = idx / 96, d = idx - ss * 96;
            Vt[d * VP + ss] = vg[(size_t)(s0 + ss) * NDH + d];
        }
        __syncthreads();

        f32x4 acc[4];
#pragma unroll
        for (int sub = 0; sub < 4; sub++) acc[sub] = (f32x4){0.f, 0.f, 0.f, 0.f};
#pragma unroll
        for (int kk = 0; kk < 3; kk++) {
#pragma unroll
            for (int sub = 0; sub < 4; sub++) {
                short8 bfr = *reinterpret_cast<const short8*>(&Kt[(sub * 16 + li) * KP + kk * 32 + g * 8]);
                acc[sub] = __builtin_amdgcn_mfma_f32_16x16x32_bf16(qf[kk], bfr, acc[sub], 0, 0, 0);
            }
        }

        float rmax[4];
#pragma unroll
        for (int rr = 0; rr < 4; rr++) rmax[rr] = -1e30f;
#pragma unroll
        for (int sub = 0; sub < 4; sub++) {
#pragma unroll
            for (int rr = 0; rr < 4; rr++) {
                int scol = s0 + sub * 16 + li;
                int qrow = q0 + w * 16 + 4 * g + rr;
                float val = acc[sub][rr];
                int dd = scol - qrow;
                if (dd >= -NW && dd <= NW) val += Rt[w * 16 + 4 * g + rr][dd + NW];
                val *= scale;
                if (scol >= len || qrow >= len) val -= 10000.f;
                acc[sub][rr] = val;
                rmax[rr] = fmaxf(rmax[rr], val);
            }
        }
#pragma unroll
        for (int off = 1; off < 16; off <<= 1) {
#pragma unroll
            for (int rr = 0; rr < 4; rr++) rmax[rr] = fmaxf(rmax[rr], __shfl_xor(rmax[rr], off));
        }

        float sc[4];
#pragma unroll
        for (int rr = 0; rr < 4; rr++) {
            float mn = fmaxf(m_run[rr], rmax[rr]);
            sc[rr] = __expf(m_run[rr] - mn);
            m_run[rr] = mn;
        }
        float rsum[4] = {0.f, 0.f, 0.f, 0.f};
#pragma unroll
        for (int sub = 0; sub < 4; sub++) {
#pragma unroll
            for (int rr = 0; rr < 4; rr++) {
                float p = __expf(acc[sub][rr] - m_run[rr]);
                acc[sub][rr] = p;
                rsum[rr] += p;
            }
        }
#pragma unroll
        for (int off = 1; off < 16; off <<= 1) {
#pragma unroll
            for (int rr = 0; rr < 4; rr++) rsum[rr] += __shfl_xor(rsum[rr], off);
        }
#pragma unroll
        for (int rr = 0; rr < 4; rr++) l_run[rr] = l_run[rr] * sc[rr] + rsum[rr];
#pragma unroll
        for (int ds = 0; ds < 6; ds++) {
#pragma unroll
            for (int rr = 0; rr < 4; rr++) Oa[ds][rr] *= sc[rr];
        }

#pragma unroll
        for (int sub = 0; sub < 4; sub++) {
#pragma unroll
            for (int rr = 0; rr < 4; rr++)
                Pt[w][(4 * g + rr) * PP + sub * 16 + li] = f2b(acc[sub][rr]);
        }

#pragma unroll
        for (int kk = 0; kk < 2; kk++) {
            short8 pa = *reinterpret_cast<const short8*>(&Pt[w][li * PP + kk * 32 + g * 8]);
#pragma unroll
            for (int ds = 0; ds < 6; ds++) {
                short8 bv = *reinterpret_cast<const short8*>(&Vt[(ds * 16 + li) * VP + kk * 32 + g * 8]);
                Oa[ds] = __builtin_amdgcn_mfma_f32_16x16x32_bf16(pa, bv, Oa[ds], 0, 0, 0);
            }
        }

#pragma unroll
        for (int rr = 0; rr < 4; rr++) {
            int qrow = q0 + w * 16 + 4 * g + rr;
#pragma unroll
            for (int dd = -NW; dd <= NW; dd++) {
                int s = qrow + dd;
                if (s >= s0 && s < s0 + 64) {
                    float p = us2f(Pt[w][(4 * g + rr) * PP + (s - s0)]);
#pragma unroll
                    for (int ds = 0; ds < 6; ds++)
                        Oa[ds][rr] += p * rvs[dd + NW][ds * 16 + li];
                }
            }
        }
    }

    float invl[4];
#pragma unroll
    for (int rr = 0; rr < 4; rr++) invl[rr] = 1.f / l_run[rr];
#pragma unroll
    for (int ds = 0; ds < 6; ds++) {
#pragma unroll
        for (int rr = 0; rr < 4; rr++) {
            int qrow = q0 + w * 16 + 4 * g + rr;
            o[((size_t)(b * NT + qrow)) * NC + h * 96 + ds * 16 + li] =
                __float2bfloat16(Oa[ds][rr] * invl[rr]);
        }
    }
}

// ---------------- x = LN(x + y) -> f32 x and bf16 mirror ----------------
__global__ __launch_bounds__(256) void add_ln_kernel(float* __restrict__ x,
                                                     bf16* __restrict__ xb,
                                                     const float* __restrict__ y,
                                                     const float* __restrict__ g,
                                                     const float* __restrict__ bb) {
    int wid = threadIdx.x >> 6;
    int lane = threadIdx.x & 63;
    int m = blockIdx.x * 4 + wid;
    size_t base = (size_t)m * NC;
    float r[3];
    float s = 0.f;
#pragma unroll
    for (int u = 0; u < 3; u++) {
        int c = lane * 3 + u;
        r[u] = x[base + c] + y[base + c];
        s += r[u];
    }
#pragma unroll
    for (int off = 32; off > 0; off >>= 1) s += __shfl_xor(s, off);
    float mu = s * (1.f / NC);
    float vs = 0.f;
#pragma unroll
    for (int u = 0; u < 3; u++) {
        float d = r[u] - mu;
        vs += d * d;
    }
#pragma unroll
    for (int off = 32; off > 0; off >>= 1) vs += __shfl_xor(vs, off);
    float rs = rsqrtf(vs * (1.f / NC) + 1e-5f);
#pragma unroll
    for (int u = 0; u < 3; u++) {
        int c = lane * 3 + u;
        float out = (r[u] - mu) * rs * g[c] + bb[c];
        x[base + c] = out;
        xb[base + c] = __float2bfloat16(out);
    }
}

// ---------------- final x^T store (masked, f32) ----------------
__global__ __launch_bounds__(256) void xpose_kernel(const float* __restrict__ x,
                                                    const int* __restrict__ lens,
                                                    float* __restrict__ out) {
    int idx = blockIdx.x * 256 + threadIdx.x;
    if (idx >= (int)MC) return;
    int t = idx % NT;
    int bc = idx / NT;
    int c = bc % NC;
    int b = bc / NC;
    float v = (t < lens[b]) ? x[((size_t)b * NT + t) * NC + c] : 0.f;
    out[idx] = v;
}

__global__ __launch_bounds__(256) void mask_kernel(const int* __restrict__ lens, float* __restrict__ out) {
    int idx = blockIdx.x * 256 + threadIdx.x;
    if (idx >= NB * NT) return;
    int t = idx % NT;
    int b = idx / NT;
    out[idx] = (t < lens[b]) ? 1.f : 0.f;
}

extern "C" void kernel_launch(void* const* d_in, const int* in_sizes, int n_in,
                              void* d_out, int out_size, void* d_ws, size_t ws_size,
                              hipStream_t stream) {
    (void)in_sizes; (void)n_in; (void)out_size; (void)ws_size;
    const int* tok = (const int*)d_in[0];
    const int* lens = (const int*)d_in[1];
    const float* emb = (const float*)d_in[2];
    const float* wqkv = (const float*)d_in[3];
    const float* bqkv = (const float*)d_in[4];
    const float* wo = (const float*)d_in[5];
    const float* bo = (const float*)d_in[6];
    const float* relk = (const float*)d_in[7];
    const float* relv = (const float*)d_in[8];
    const float* ln1g = (const float*)d_in[9];
    const float* ln1b = (const float*)d_in[10];
    const float* ln2g = (const float*)d_in[11];
    const float* ln2b = (const float*)d_in[12];
    const float* fw1 = (const float*)d_in[13];
    const float* fb1 = (const float*)d_in[14];
    const float* fw2 = (const float*)d_in[15];
    const float* fb2 = (const float*)d_in[16];
    const float* pw = (const float*)d_in[17];
    const float* pb = (const float*)d_in[18];
    float* out = (float*)d_out;

    char* wsb = (char*)d_ws;
    float* xB = (float*)wsb;                       // f32 [M][C]
    float* yB = (float*)(wsb + MCB);               // f32 [M][C]
    bf16* xb = (bf16*)(wsb + 2 * MCB);             // bf16 [M][C]
    bf16* qb = (bf16*)(wsb + 2 * MCB + MCB / 2);   // bf16 [BH][T][DH]
    bf16* kb = qb + MC;
    bf16* vb = kb + MC;
    bf16* ob = vb + MC;
    bf16* hB = qb;                                 // alias: bf16 [M][DFF] == qb..ob
    bf16* pwqkv = ob + MC;                         // weights (bf16)
    bf16* pwo = pwqkv + (size_t)NLAYER * 3 * NC * NC;
    bf16* pw1 = pwo + (size_t)NLAYER * NC * NC;
    bf16* pw2 = pw1 + (size_t)NLAYER * 3 * NDFF * NC;
    bf16* pproj = pw2 + (size_t)NLAYER * 3 * NC * NDFF;

    // weight conversion (bf16 / conv-permuted)
    {
        int n1 = NLAYER * 3 * NC * NC;
        cvt_plain<<<(n1 + 255) / 256, 256, 0, stream>>>(wqkv, pwqkv, n1);
        int n2 = NLAYER * NC * NC;
        cvt_plain<<<(n2 + 255) / 256, 256, 0, stream>>>(wo, pwo, n2);
        int n3 = 2 * 192 * NC;
        cvt_plain<<<(n3 + 255) / 256, 256, 0, stream>>>(pw, pproj, n3);
        int n4 = NLAYER * NDFF * NC * 3;
        cvt_conv<<<(n4 + 255) / 256, 256, 0, stream>>>(fw1, pw1, NLAYER, NDFF, NC);
        int n5 = NLAYER * NC * NDFF * 3;
        cvt_conv<<<(n5 + 255) / 256, 256, 0, stream>>>(fw2, pw2, NLAYER, NC, NDFF);
    }

    embed_kernel<<<(int)((MC + 255) / 256), 256, 0, stream>>>(tok, lens, emb, xB, xb);

    for (int l = 0; l < NLAYER; l++) {
        gemm_mfma<GM_QKV, 576, 192, 1><<<dim3(9, 256), 256, 0, stream>>>(
            xb, pwqkv + (size_t)l * 3 * NC * NC, bqkv + (size_t)l * 3 * NC, lens,
            nullptr, qb, kb, vb);
        attn_mfma<<<dim3(8, NB * NHEAD), 256, 0, stream>>>(
            qb, kb, vb, relk + (size_t)l * (2 * NW + 1) * NDH,
            relv + (size_t)l * (2 * NW + 1) * NDH, lens, ob);
        gemm_mfma<GM_OPROJ, 192, 192, 1><<<dim3(3, 256), 256, 0, stream>>>(
            ob, pwo + (size_t)l * NC * NC, bo + (size_t)l * NC, lens,
            yB, nullptr, nullptr, nullptr);
        add_ln_kernel<<<MROWS / 4, 256, 0, stream>>>(xB, xb, yB, ln1g + (size_t)l * NC, ln1b + (size_t)l * NC);
        gemm_mfma<GM_CONV1, 768, 192, 3><<<dim3(12, 256), 256, 0, stream>>>(
            xb, pw1 + (size_t)l * 3 * NDFF * NC, fb1 + (size_t)l * NDFF, lens,
            nullptr, hB, nullptr, nullptr);
        gemm_mfma<GM_CONV2, 192, 768, 3><<<dim3(3, 256), 256, 0, stream>>>(
            hB, pw2 + (size_t)l * 3 * NC * NDFF, fb2 + (size_t)l * NC, lens,
            yB, nullptr, nullptr, nullptr);
        add_ln_kernel<<<MROWS / 4, 256, 0, stream>>>(xB, xb, yB, ln2g + (size_t)l * NC, ln2b + (size_t)l * NC);
    }

    gemm_mfma<GM_PROJ, 384, 192, 1><<<dim3(6, 256), 256, 0, stream>>>(
        xb, pproj, pb, lens, out, nullptr, nullptr, nullptr);
    xpose_kernel<<<(int)((MC + 255) / 256), 256, 0, stream>>>(xB, lens, out);
    mask_kernel<<<(NB * NT + 255) / 256, 256, 0, stream>>>(lens, out + 3 * MC);
}

// Round 6
// 1982.063 us; speedup vs baseline: 9.4793x; 1.1642x over previous
//
#include <hip/hip_runtime.h>
#include <hip/hip_bf16.h>

typedef __hip_bfloat16 bf16;
typedef __attribute__((ext_vector_type(8))) short short8;
typedef __attribute__((ext_vector_type(4))) float f32x4;

#define NB 64
#define NT 512
#define NC 192
#define NHEAD 2
#define NDH 96
#define NLAYER 6
#define NDFF 768
#define NW 4

constexpr int MROWS = NB * NT;            // 32768
constexpr size_t MC = (size_t)MROWS * NC; // 6291456
constexpr size_t MCB = MC * 4;

__device__ __forceinline__ float us2f(unsigned short x) { return __uint_as_float((unsigned)x << 16); }
__device__ __forceinline__ unsigned short f2b(float f) {
    bf16 h = __float2bfloat16(f);
    return *reinterpret_cast<unsigned short*>(&h);
}

// ---------------- weight conversion ----------------
__global__ __launch_bounds__(256) void cvt_plain(const float* __restrict__ s, bf16* __restrict__ d, int n) {
    int i = blockIdx.x * 256 + threadIdx.x;
    if (i < n) d[i] = __float2bfloat16(s[i]);
}
// [L][N][C][3] f32 -> [L][3][N][C] bf16
__global__ __launch_bounds__(256) void cvt_conv(const float* __restrict__ s, bf16* __restrict__ d,
                                                int L, int N, int C) {
    int i = blockIdx.x * 256 + threadIdx.x;
    if (i >= L * N * C * 3) return;
    int dk = i % 3;
    int rest = i / 3;
    int c = rest % C;
    int rest2 = rest / C;
    int n = rest2 % N;
    int l = rest2 / N;
    d[(((size_t)l * 3 + dk) * N + n) * C + c] = __float2bfloat16(s[i]);
}

// ---------------- embedding ----------------
__global__ __launch_bounds__(256) void embed_kernel(const int* __restrict__ tok,
                                                    const int* __restrict__ lens,
                                                    const float* __restrict__ emb,
                                                    float* __restrict__ x,
                                                    bf16* __restrict__ xb) {
    int idx = blockIdx.x * 256 + threadIdx.x;
    if (idx >= (int)MC) return;
    int c = idx % NC;
    int m = idx / NC;
    int t = m % NT, b = m / NT;
    float v = emb[tok[m] * NC + c] * 13.856406460551018f; // sqrt(192)
    if (t >= lens[b]) v = 0.f;
    x[idx] = v;
    xb[idx] = __float2bfloat16(v);
}

// ---------------- plain MFMA GEMM (QKV / CONV1 / PROJ), tap-folded ----------------
enum GMode { GM_QKV = 0, GM_CONV1 = 2, GM_PROJ = 4 };

template <int MODE, int NTOT, int KC, int TAPS>
__global__ __launch_bounds__(256) void gemm_mfma(const bf16* __restrict__ A,
                                                 const bf16* __restrict__ W,
                                                 const float* __restrict__ bias,
                                                 const int* __restrict__ lens,
                                                 float* __restrict__ of,
                                                 bf16* __restrict__ ob1,
                                                 bf16* __restrict__ ob2,
                                                 bf16* __restrict__ ob3) {
    constexpr int RA = (TAPS == 3) ? 130 : 128;
    constexpr int RB = TAPS * 64;
    __shared__ unsigned short As[RA * 40];
    __shared__ unsigned short Bs[RB * 40];
    const int tid = threadIdx.x;
    const int w = tid >> 6, lane = tid & 63;
    const int g = lane >> 4, li = lane & 15;
    const int n0 = blockIdx.x * 64;
    const int m0 = blockIdx.y * 128;
    const int b = m0 >> 9, t0 = m0 & 511;
    const int len = lens[b];
    const unsigned short* Au = (const unsigned short*)A;
    const unsigned short* Wu = (const unsigned short*)W;

    f32x4 acc[2][4];
#pragma unroll
    for (int a = 0; a < 2; a++)
#pragma unroll
        for (int s = 0; s < 4; s++) acc[a][s] = (f32x4){0.f, 0.f, 0.f, 0.f};

#pragma unroll 1
    for (int k0 = 0; k0 < KC; k0 += 32) {
        __syncthreads();
        for (int c = tid; c < RA * 2; c += 256) {
            int i = c >> 1, hf = (c & 1) * 16;
            int t = t0 + i - (TAPS == 3 ? 1 : 0);
            bool valid = (t >= 0) && (t < NT);
            if constexpr (MODE == GM_CONV1) valid = valid && (t < len);
            short8 v0{}, v1{};
            if (valid) {
                const unsigned short* src = Au + ((size_t)(b * NT + t) * KC + k0 + hf);
                v0 = *(const short8*)src;
                v1 = *(const short8*)(src + 8);
            }
            *(short8*)&As[i * 40 + hf] = v0;
            *(short8*)&As[i * 40 + hf + 8] = v1;
        }
        for (int c = tid; c < RB * 4; c += 256) {
            int rb = c >> 2, qq = (c & 3) * 8;
            int dk = rb >> 6, nl = rb & 63;
            *(short8*)&Bs[rb * 40 + qq] =
                *(const short8*)(Wu + ((size_t)(dk * NTOT + n0 + nl) * KC + k0 + qq));
        }
        __syncthreads();
#pragma unroll
        for (int dk = 0; dk < TAPS; dk++) {
            short8 af0 = *(const short8*)&As[(w * 32 + li + dk) * 40 + g * 8];
            short8 af1 = *(const short8*)&As[(w * 32 + 16 + li + dk) * 40 + g * 8];
#pragma unroll
            for (int sub = 0; sub < 4; sub++) {
                short8 bfr = *(const short8*)&Bs[(dk * 64 + sub * 16 + li) * 40 + g * 8];
                acc[0][sub] = __builtin_amdgcn_mfma_f32_16x16x32_bf16(af0, bfr, acc[0][sub], 0, 0, 0);
                acc[1][sub] = __builtin_amdgcn_mfma_f32_16x16x32_bf16(af1, bfr, acc[1][sub], 0, 0, 0);
            }
        }
    }

#pragma unroll
    for (int sub = 0; sub < 4; sub++) {
        int n = n0 + sub * 16 + li;
        float bv = bias[n];
#pragma unroll
        for (int a = 0; a < 2; a++) {
#pragma unroll
            for (int rr = 0; rr < 4; rr++) {
                int t = t0 + w * 32 + a * 16 + g * 4 + rr;
                size_t m = (size_t)(b * NT + t);
                float vv = acc[a][sub][rr] + bv;
                if constexpr (MODE == GM_QKV) {
                    int iw = n / NC;
                    int cc = n - iw * NC;
                    int hh = cc >= NDH ? 1 : 0;
                    int d = cc - hh * NDH;
                    int bh = b * NHEAD + hh;
                    if (iw == 0) ob1[((size_t)bh * NT + t) * NDH + d] = __float2bfloat16(vv);
                    else if (iw == 1) ob2[((size_t)bh * NT + t) * NDH + d] = __float2bfloat16(vv);
                    else ob3[((size_t)bh * NDH + d) * NT + t] = __float2bfloat16(vv); // V^T
                } else if constexpr (MODE == GM_CONV1) {
                    vv = vv > 0.f ? vv : 0.f;
                    if (t >= len) vv = 0.f;
                    ob1[m * NDFF + n] = __float2bfloat16(vv);
                } else { // GM_PROJ
                    if (t >= len) vv = 0.f;
                    int half = n >= 192 ? 1 : 0;
                    int cc = n - half * 192;
                    of[(size_t)(half + 1) * MC + ((size_t)b * NC + cc) * NT + t] = vv;
                }
            }
        }
    }
}

// ---------------- fused GEMM + residual + LayerNorm (OPROJ / CONV2) ----------------
template <int KC, int TAPS, bool MASKY>
__global__ __launch_bounds__(256) void gemm_ln(const bf16* __restrict__ A,
                                               const bf16* __restrict__ W,
                                               const float* __restrict__ bias,
                                               const int* __restrict__ lens,
                                               const float* __restrict__ lng,
                                               const float* __restrict__ lnb,
                                               float* __restrict__ x,
                                               bf16* __restrict__ xb) {
    constexpr int RA = (TAPS == 3) ? 66 : 64;
    constexpr int RB = TAPS * 192;
    __shared__ unsigned short As[RA * 40];
    __shared__ unsigned short Bs[RB * 40];
    const int tid = threadIdx.x;
    const int w = tid >> 6, lane = tid & 63;
    const int g = lane >> 4, li = lane & 15;
    const int m0 = blockIdx.x * 64;
    const int b = m0 >> 9, t0 = m0 & 511;
    const int len = lens[b];
    const unsigned short* Au = (const unsigned short*)A;
    const unsigned short* Wu = (const unsigned short*)W;

    f32x4 acc[12];
#pragma unroll
    for (int s = 0; s < 12; s++) acc[s] = (f32x4){0.f, 0.f, 0.f, 0.f};

#pragma unroll 1
    for (int k0 = 0; k0 < KC; k0 += 32) {
        __syncthreads();
        for (int c = tid; c < RA * 2; c += 256) {
            int i = c >> 1, hf = (c & 1) * 16;
            int t = t0 + i - (TAPS == 3 ? 1 : 0);
            bool valid = (t >= 0) && (t < NT);
            short8 v0{}, v1{};
            if (valid) {
                const unsigned short* src = Au + ((size_t)(b * NT + t) * KC + k0 + hf);
                v0 = *(const short8*)src;
                v1 = *(const short8*)(src + 8);
            }
            *(short8*)&As[i * 40 + hf] = v0;
            *(short8*)&As[i * 40 + hf + 8] = v1;
        }
        for (int c = tid; c < RB * 4; c += 256) {
            int rb = c >> 2, qq = (c & 3) * 8;
            *(short8*)&Bs[rb * 40 + qq] = *(const short8*)(Wu + ((size_t)rb * KC + k0 + qq));
        }
        __syncthreads();
#pragma unroll
        for (int dk = 0; dk < TAPS; dk++) {
            short8 af = *(const short8*)&As[(w * 16 + li + dk) * 40 + g * 8];
#pragma unroll
            for (int sub = 0; sub < 12; sub++) {
                short8 bfr = *(const short8*)&Bs[(dk * 192 + sub * 16 + li) * 40 + g * 8];
                acc[sub] = __builtin_amdgcn_mfma_f32_16x16x32_bf16(af, bfr, acc[sub], 0, 0, 0);
            }
        }
    }

    // epilogue: residual + LN. row = w*16 + 4g + rr, col = sub*16 + li
    float biasv[12], gv[12], bbv[12];
#pragma unroll
    for (int sub = 0; sub < 12; sub++) {
        int n = sub * 16 + li;
        biasv[sub] = bias[n];
        gv[sub] = lng[n];
        bbv[sub] = lnb[n];
    }
    float sm[4] = {0.f, 0.f, 0.f, 0.f}, sq[4] = {0.f, 0.f, 0.f, 0.f};
#pragma unroll
    for (int rr = 0; rr < 4; rr++) {
        int t = t0 + w * 16 + 4 * g + rr;
        size_t m = (size_t)(b * NT + t);
#pragma unroll
        for (int sub = 0; sub < 12; sub++) {
            float y = acc[sub][rr] + biasv[sub];
            if (MASKY && t >= len) y = 0.f;
            float r = y + x[m * NC + sub * 16 + li];
            acc[sub][rr] = r;
            sm[rr] += r;
            sq[rr] += r * r;
        }
    }
#pragma unroll
    for (int off = 1; off < 16; off <<= 1) {
#pragma unroll
        for (int rr = 0; rr < 4; rr++) {
            sm[rr] += __shfl_xor(sm[rr], off);
            sq[rr] += __shfl_xor(sq[rr], off);
        }
    }
#pragma unroll
    for (int rr = 0; rr < 4; rr++) {
        int t = t0 + w * 16 + 4 * g + rr;
        size_t m = (size_t)(b * NT + t);
        float mu = sm[rr] * (1.f / NC);
        float var = fmaxf(sq[rr] * (1.f / NC) - mu * mu, 0.f);
        float rs = rsqrtf(var + 1e-5f);
#pragma unroll
        for (int sub = 0; sub < 12; sub++) {
            float o = (acc[sub][rr] - mu) * rs * gv[sub] + bbv[sub];
            x[m * NC + sub * 16 + li] = o;
            xb[m * NC + sub * 16 + li] = __float2bfloat16(o);
        }
    }
}

// ---------------- MFMA flash attention v2: q-tile 128, V^T input, MFMA rel-K/rel-V ----------------
__global__ __launch_bounds__(256) void attn_mfma(const bf16* __restrict__ q,
                                                 const bf16* __restrict__ k,
                                                 const bf16* __restrict__ v,
                                                 const float* __restrict__ relk,
                                                 const float* __restrict__ relv,
                                                 const int* __restrict__ lens,
                                                 bf16* __restrict__ o) {
    __shared__ __align__(16) char pool[64512];
    float* Rt = (float*)pool;                                    // [128][9] f32
    unsigned short* RvT = (unsigned short*)(pool + 4608);        // [96][32] (j pad to 32, zeros)
    unsigned short* Qt = (unsigned short*)(pool + 10752);        // [128][104] (prologue only)
    unsigned short* Rk = (unsigned short*)(pool + 37376);        // [16][104] (prologue only)
    unsigned short* Kt = (unsigned short*)(pool + 10752);        // [64][104]
    unsigned short* Vt = (unsigned short*)(pool + 24064);        // [96][72]
    unsigned short* Pt = (unsigned short*)(pool + 37888);        // [4][32][72]
    unsigned short* Pb = (unsigned short*)(pool + 56320);        // [4][2][16][32]

    const int qt = blockIdx.x, bh = blockIdx.y;
    const int b = bh >> 1, h = bh & 1;
    const int q0 = qt * 128;
    const int tid = threadIdx.x;
    const int w = tid >> 6, lane = tid & 63;
    const int g = lane >> 4, li = lane & 15;
    const int len = lens[b];
    const float scale = 0.10206207261596575f; // 1/sqrt(96)

    const unsigned short* qg = (const unsigned short*)q + (size_t)bh * NT * NDH;
    const unsigned short* kg = (const unsigned short*)k + (size_t)bh * NT * NDH;
    const unsigned short* vg = (const unsigned short*)v + (size_t)bh * NDH * NT; // V^T [96][512]

    // ---- prologue staging ----
    for (int c = tid; c < 128 * 12; c += 256) {
        int r = c / 12, seg = (c % 12) * 8;
        *(short8*)&Qt[r * 104 + seg] = *(const short8*)(qg + (size_t)(q0 + r) * NDH + seg);
    }
    for (int c = tid; c < 16 * 96; c += 256) {
        int dd = c / 96, d = c - (c / 96) * 96;
        Rk[dd * 104 + d] = (dd < 9) ? f2b(relk[dd * 96 + d]) : (unsigned short)0;
    }
    for (int c = tid; c < 96 * 32; c += 256) {
        int d = c >> 5, j = c & 31;
        RvT[d * 32 + j] = (j < 9) ? f2b(relv[j * 96 + d]) : (unsigned short)0;
    }
    for (int c = tid; c < 4 * 2 * 16 * 32; c += 256) Pb[c] = 0;
    __syncthreads();

    // ---- Rt = Q . relK^T via MFMA ----
    {
        f32x4 racc[2];
        racc[0] = (f32x4){0.f, 0.f, 0.f, 0.f};
        racc[1] = (f32x4){0.f, 0.f, 0.f, 0.f};
#pragma unroll
        for (int a = 0; a < 2; a++)
#pragma unroll
            for (int kk = 0; kk < 3; kk++) {
                short8 af = *(const short8*)&Qt[(w * 32 + a * 16 + li) * 104 + kk * 32 + g * 8];
                short8 bfr = *(const short8*)&Rk[li * 104 + kk * 32 + g * 8];
                racc[a] = __builtin_amdgcn_mfma_f32_16x16x32_bf16(af, bfr, racc[a], 0, 0, 0);
            }
        if (li < 9) {
#pragma unroll
            for (int a = 0; a < 2; a++)
#pragma unroll
                for (int rr = 0; rr < 4; rr++)
                    Rt[(w * 32 + a * 16 + 4 * g + rr) * 9 + li] = racc[a][rr];
        }
    }
    // ---- fragments ----
    short8 qf[2][3], rvf[6];
#pragma unroll
    for (int a = 0; a < 2; a++)
#pragma unroll
        for (int kk = 0; kk < 3; kk++)
            qf[a][kk] = *(const short8*)&Qt[(w * 32 + a * 16 + li) * 104 + kk * 32 + g * 8];
#pragma unroll
    for (int ds = 0; ds < 6; ds++)
        rvf[ds] = *(const short8*)&RvT[(ds * 16 + li) * 32 + g * 8];
    __syncthreads();

    float m_run[2][4], l_run[2][4];
    f32x4 Oa[2][6];
#pragma unroll
    for (int a = 0; a < 2; a++) {
#pragma unroll
        for (int rr = 0; rr < 4; rr++) { m_run[a][rr] = -1e30f; l_run[a][rr] = 0.f; }
#pragma unroll
        for (int ds = 0; ds < 6; ds++) Oa[a][ds] = (f32x4){0.f, 0.f, 0.f, 0.f};
    }

    for (int s0 = 0; s0 < NT; s0 += 64) {
        for (int c = tid; c < 64 * 12; c += 256) {
            int ss = c / 12, seg = (c % 12) * 8;
            *(short8*)&Kt[ss * 104 + seg] = *(const short8*)(kg + (size_t)(s0 + ss) * NDH + seg);
        }
        for (int c = tid; c < 96 * 8; c += 256) {
            int d = c >> 3, seg = (c & 7) * 8;
            *(short8*)&Vt[d * 72 + seg] = *(const short8*)(vg + (size_t)d * NT + s0 + seg);
        }
        __syncthreads();

        // ---- S = Q K^T ----
        f32x4 acc[2][4];
#pragma unroll
        for (int a = 0; a < 2; a++)
#pragma unroll
            for (int sub = 0; sub < 4; sub++) acc[a][sub] = (f32x4){0.f, 0.f, 0.f, 0.f};
        __builtin_amdgcn_s_setprio(1);
#pragma unroll
        for (int kk = 0; kk < 3; kk++) {
#pragma unroll
            for (int sub = 0; sub < 4; sub++) {
                short8 bfr = *(const short8*)&Kt[(sub * 16 + li) * 104 + kk * 32 + g * 8];
                acc[0][sub] = __builtin_amdgcn_mfma_f32_16x16x32_bf16(qf[0][kk], bfr, acc[0][sub], 0, 0, 0);
                acc[1][sub] = __builtin_amdgcn_mfma_f32_16x16x32_bf16(qf[1][kk], bfr, acc[1][sub], 0, 0, 0);
            }
        }
        __builtin_amdgcn_s_setprio(0);

        // ---- rel-K band + scale + mask + rowmax ----
        float rmax[2][4];
#pragma unroll
        for (int a = 0; a < 2; a++)
#pragma unroll
            for (int rr = 0; rr < 4; rr++) rmax[a][rr] = -1e30f;
#pragma unroll
        for (int a = 0; a < 2; a++) {
#pragma unroll
            for (int sub = 0; sub < 4; sub++) {
#pragma unroll
                for (int rr = 0; rr < 4; rr++) {
                    int scol = s0 + sub * 16 + li;
                    int rloc = w * 32 + a * 16 + 4 * g + rr;
                    int qrow = q0 + rloc;
                    float val = acc[a][sub][rr];
                    int dd = scol - qrow;
                    if (dd >= -NW && dd <= NW) val += Rt[rloc * 9 + dd + NW];
                    val *= scale;
                    if (scol >= len || qrow >= len) val -= 10000.f;
                    acc[a][sub][rr] = val;
                    rmax[a][rr] = fmaxf(rmax[a][rr], val);
                }
            }
        }
#pragma unroll
        for (int off = 1; off < 16; off <<= 1)
#pragma unroll
            for (int a = 0; a < 2; a++)
#pragma unroll
                for (int rr = 0; rr < 4; rr++) rmax[a][rr] = fmaxf(rmax[a][rr], __shfl_xor(rmax[a][rr], off));

        // ---- online softmax ----
        float scf[2][4];
#pragma unroll
        for (int a = 0; a < 2; a++)
#pragma unroll
            for (int rr = 0; rr < 4; rr++) {
                float mn = fmaxf(m_run[a][rr], rmax[a][rr]);
                scf[a][rr] = __expf(m_run[a][rr] - mn);
                m_run[a][rr] = mn;
            }
        float rsum[2][4] = {};
#pragma unroll
        for (int a = 0; a < 2; a++)
#pragma unroll
            for (int sub = 0; sub < 4; sub++)
#pragma unroll
                for (int rr = 0; rr < 4; rr++) {
                    float p = __expf(acc[a][sub][rr] - m_run[a][rr]);
                    acc[a][sub][rr] = p;
                    rsum[a][rr] += p;
                }
#pragma unroll
        for (int off = 1; off < 16; off <<= 1)
#pragma unroll
            for (int a = 0; a < 2; a++)
#pragma unroll
                for (int rr = 0; rr < 4; rr++) rsum[a][rr] += __shfl_xor(rsum[a][rr], off);
#pragma unroll
        for (int a = 0; a < 2; a++) {
#pragma unroll
            for (int rr = 0; rr < 4; rr++) l_run[a][rr] = l_run[a][rr] * scf[a][rr] + rsum[a][rr];
#pragma unroll
            for (int ds = 0; ds < 6; ds++)
#pragma unroll
                for (int rr = 0; rr < 4; rr++) Oa[a][ds][rr] *= scf[a][rr];
        }

        // ---- P -> LDS (per-wave) ----
#pragma unroll
        for (int a = 0; a < 2; a++)
#pragma unroll
            for (int sub = 0; sub < 4; sub++)
#pragma unroll
                for (int rr = 0; rr < 4; rr++)
                    Pt[w * 2304 + (a * 16 + 4 * g + rr) * 72 + sub * 16 + li] = f2b(acc[a][sub][rr]);

        // ---- O += P V ----
        __builtin_amdgcn_s_setprio(1);
#pragma unroll
        for (int kk = 0; kk < 2; kk++) {
            short8 pa0 = *(const short8*)&Pt[w * 2304 + (li) * 72 + kk * 32 + g * 8];
            short8 pa1 = *(const short8*)&Pt[w * 2304 + (16 + li) * 72 + kk * 32 + g * 8];
#pragma unroll
            for (int ds = 0; ds < 6; ds++) {
                short8 bv = *(const short8*)&Vt[(ds * 16 + li) * 72 + kk * 32 + g * 8];
                Oa[0][ds] = __builtin_amdgcn_mfma_f32_16x16x32_bf16(pa0, bv, Oa[0][ds], 0, 0, 0);
                Oa[1][ds] = __builtin_amdgcn_mfma_f32_16x16x32_bf16(pa1, bv, Oa[1][ds], 0, 0, 0);
            }
        }
        __builtin_amdgcn_s_setprio(0);

        // ---- rel-V via MFMA: O += Pband . RvT ----
#pragma unroll
        for (int a = 0; a < 2; a++) {
            for (int c = lane; c < 144; c += 64) {
                int r = c / 9, j = c - (c / 9) * 9;
                int s = q0 + w * 32 + a * 16 + r + j - NW;
                unsigned short pv_ = 0;
                int u = s - s0;
                if (u >= 0 && u < 64) pv_ = Pt[w * 2304 + (a * 16 + r) * 72 + u];
                Pb[(w * 2 + a) * 512 + r * 32 + j] = pv_;
            }
            short8 pband = *(const short8*)&Pb[(w * 2 + a) * 512 + li * 32 + g * 8];
#pragma unroll
            for (int ds = 0; ds < 6; ds++)
                Oa[a][ds] = __builtin_amdgcn_mfma_f32_16x16x32_bf16(pband, rvf[ds], Oa[a][ds], 0, 0, 0);
        }
        __syncthreads();
    }

#pragma unroll
    for (int a = 0; a < 2; a++) {
        float invl[4];
#pragma unroll
        for (int rr = 0; rr < 4; rr++) invl[rr] = 1.f / l_run[a][rr];
#pragma unroll
        for (int ds = 0; ds < 6; ds++)
#pragma unroll
            for (int rr = 0; rr < 4; rr++) {
                int qrow = q0 + w * 32 + a * 16 + 4 * g + rr;
                o[((size_t)(b * NT + qrow)) * NC + h * 96 + ds * 16 + li] =
                    __float2bfloat16(Oa[a][ds][rr] * invl[rr]);
            }
    }
}

// ---------------- final x^T store (masked, f32) ----------------
__global__ __launch_bounds__(256) void xpose_kernel(const float* __restrict__ x,
                                                    const int* __restrict__ lens,
                                                    float* __restrict__ out) {
    int idx = blockIdx.x * 256 + threadIdx.x;
    if (idx >= (int)MC) return;
    int t = idx % NT;
    int bc = idx / NT;
    int c = bc % NC;
    int b = bc / NC;
    float v = (t < lens[b]) ? x[((size_t)b * NT + t) * NC + c] : 0.f;
    out[idx] = v;
}

__global__ __launch_bounds__(256) void mask_kernel(const int* __restrict__ lens, float* __restrict__ out) {
    int idx = blockIdx.x * 256 + threadIdx.x;
    if (idx >= NB * NT) return;
    int t = idx % NT;
    int b = idx / NT;
    out[idx] = (t < lens[b]) ? 1.f : 0.f;
}

extern "C" void kernel_launch(void* const* d_in, const int* in_sizes, int n_in,
                              void* d_out, int out_size, void* d_ws, size_t ws_size,
                              hipStream_t stream) {
    (void)in_sizes; (void)n_in; (void)out_size; (void)ws_size;
    const int* tok = (const int*)d_in[0];
    const int* lens = (const int*)d_in[1];
    const float* emb = (const float*)d_in[2];
    const float* wqkv = (const float*)d_in[3];
    const float* bqkv = (const float*)d_in[4];
    const float* wo = (const float*)d_in[5];
    const float* bo = (const float*)d_in[6];
    const float* relk = (const float*)d_in[7];
    const float* relv = (const float*)d_in[8];
    const float* ln1g = (const float*)d_in[9];
    const float* ln1b = (const float*)d_in[10];
    const float* ln2g = (const float*)d_in[11];
    const float* ln2b = (const float*)d_in[12];
    const float* fw1 = (const float*)d_in[13];
    const float* fb1 = (const float*)d_in[14];
    const float* fw2 = (const float*)d_in[15];
    const float* fb2 = (const float*)d_in[16];
    const float* pw = (const float*)d_in[17];
    const float* pb = (const float*)d_in[18];
    float* out = (float*)d_out;

    char* wsb = (char*)d_ws;
    float* xB = (float*)wsb;                       // f32 [M][C]
    float* yUnused = (float*)(wsb + MCB);          // kept for layout stability (unused)
    bf16* xb = (bf16*)(wsb + 2 * MCB);             // bf16 [M][C]
    bf16* qb = (bf16*)(wsb + 2 * MCB + MCB / 2);   // bf16 [BH][T][DH]
    bf16* kb = qb + MC;
    bf16* vb = kb + MC;                            // stored transposed: [BH][DH][T]
    bf16* ob = vb + MC;
    bf16* hB = qb;                                 // alias: bf16 [M][DFF] over qb..ob
    bf16* pwqkv = ob + MC;
    bf16* pwo = pwqkv + (size_t)NLAYER * 3 * NC * NC;
    bf16* pw1 = pwo + (size_t)NLAYER * NC * NC;
    bf16* pw2 = pw1 + (size_t)NLAYER * 3 * NDFF * NC;
    bf16* pproj = pw2 + (size_t)NLAYER * 3 * NC * NDFF;
    (void)yUnused;

    {
        int n1 = NLAYER * 3 * NC * NC;
        cvt_plain<<<(n1 + 255) / 256, 256, 0, stream>>>(wqkv, pwqkv, n1);
        int n2 = NLAYER * NC * NC;
        cvt_plain<<<(n2 + 255) / 256, 256, 0, stream>>>(wo, pwo, n2);
        int n3 = 2 * 192 * NC;
        cvt_plain<<<(n3 + 255) / 256, 256, 0, stream>>>(pw, pproj, n3);
        int n4 = NLAYER * NDFF * NC * 3;
        cvt_conv<<<(n4 + 255) / 256, 256, 0, stream>>>(fw1, pw1, NLAYER, NDFF, NC);
        int n5 = NLAYER * NC * NDFF * 3;
        cvt_conv<<<(n5 + 255) / 256, 256, 0, stream>>>(fw2, pw2, NLAYER, NC, NDFF);
    }

    embed_kernel<<<(int)((MC + 255) / 256), 256, 0, stream>>>(tok, lens, emb, xB, xb);

    for (int l = 0; l < NLAYER; l++) {
        gemm_mfma<GM_QKV, 576, 192, 1><<<dim3(9, 256), 256, 0, stream>>>(
            xb, pwqkv + (size_t)l * 3 * NC * NC, bqkv + (size_t)l * 3 * NC, lens,
            nullptr, qb, kb, vb);
        attn_mfma<<<dim3(4, NB * NHEAD), 256, 0, stream>>>(
            qb, kb, vb, relk + (size_t)l * (2 * NW + 1) * NDH,
            relv + (size_t)l * (2 * NW + 1) * NDH, lens, ob);
        gemm_ln<192, 1, false><<<512, 256, 0, stream>>>(
            ob, pwo + (size_t)l * NC * NC, bo + (size_t)l * NC, lens,
            ln1g + (size_t)l * NC, ln1b + (size_t)l * NC, xB, xb);
        gemm_mfma<GM_CONV1, 768, 192, 3><<<dim3(12, 256), 256, 0, stream>>>(
            xb, pw1 + (size_t)l * 3 * NDFF * NC, fb1 + (size_t)l * NDFF, lens,
            nullptr, hB, nullptr, nullptr);
        gemm_ln<768, 3, true><<<512, 256, 0, stream>>>(
            hB, pw2 + (size_t)l * 3 * NC * NDFF, fb2 + (size_t)l * NC, lens,
            ln2g + (size_t)l * NC, ln2b + (size_t)l * NC, xB, xb);
    }

    gemm_mfma<GM_PROJ, 384, 192, 1><<<dim3(6, 256), 256, 0, stream>>>(
        xb, pproj, pb, lens, out, nullptr, nullptr, nullptr);
    xpose_kernel<<<(int)((MC + 255) / 256), 256, 0, stream>>>(xB, lens, out);
    mask_kernel<<<(NB * NT + 255) / 256, 256, 0, stream>>>(lens, out + 3 * MC);
}

// Round 7
// 1745.558 us; speedup vs baseline: 10.7637x; 1.1355x over previous
//
#include <hip/hip_runtime.h>
#include <hip/hip_bf16.h>

typedef __hip_bfloat16 bf16;
typedef __attribute__((ext_vector_type(8))) short short8;
typedef __attribute__((ext_vector_type(4))) float f32x4;

#define NB 64
#define NT 512
#define NC 192
#define NHEAD 2
#define NDH 96
#define NLAYER 6
#define NDFF 768
#define NW 4

constexpr int MROWS = NB * NT;            // 32768
constexpr size_t MC = (size_t)MROWS * NC; // 6291456
constexpr size_t MCB = MC * 4;

__device__ __forceinline__ float us2f(unsigned short x) { return __uint_as_float((unsigned)x << 16); }
__device__ __forceinline__ unsigned short f2b(float f) {
    bf16 h = __float2bfloat16(f);
    return *reinterpret_cast<unsigned short*>(&h);
}

// ---------------- weight conversion ----------------
__global__ __launch_bounds__(256) void cvt_plain(const float* __restrict__ s, bf16* __restrict__ d, int n) {
    int i = blockIdx.x * 256 + threadIdx.x;
    if (i < n) d[i] = __float2bfloat16(s[i]);
}
// [L][N][C][3] f32 -> [L][3][N][C] bf16
__global__ __launch_bounds__(256) void cvt_conv(const float* __restrict__ s, bf16* __restrict__ d,
                                                int L, int N, int C) {
    int i = blockIdx.x * 256 + threadIdx.x;
    if (i >= L * N * C * 3) return;
    int dk = i % 3;
    int rest = i / 3;
    int c = rest % C;
    int rest2 = rest / C;
    int n = rest2 % N;
    int l = rest2 / N;
    d[(((size_t)l * 3 + dk) * N + n) * C + c] = __float2bfloat16(s[i]);
}

// ---------------- embedding ----------------
__global__ __launch_bounds__(256) void embed_kernel(const int* __restrict__ tok,
                                                    const int* __restrict__ lens,
                                                    const float* __restrict__ emb,
                                                    float* __restrict__ x,
                                                    bf16* __restrict__ xb) {
    int idx = blockIdx.x * 256 + threadIdx.x;
    if (idx >= (int)MC) return;
    int c = idx % NC;
    int m = idx / NC;
    int t = m % NT, b = m / NT;
    float v = emb[tok[m] * NC + c] * 13.856406460551018f; // sqrt(192)
    if (t >= lens[b]) v = 0.f;
    x[idx] = v;
    xb[idx] = __float2bfloat16(v);
}

// ---------------- plain MFMA GEMM (QKV / CONV1 / PROJ), tap-folded ----------------
enum GMode { GM_QKV = 0, GM_CONV1 = 2, GM_PROJ = 4 };

template <int MODE, int NTOT, int KC, int TAPS>
__global__ __launch_bounds__(256) void gemm_mfma(const bf16* __restrict__ A,
                                                 const bf16* __restrict__ W,
                                                 const float* __restrict__ bias,
                                                 const int* __restrict__ lens,
                                                 float* __restrict__ of,
                                                 bf16* __restrict__ ob1,
                                                 bf16* __restrict__ ob2,
                                                 bf16* __restrict__ ob3) {
    constexpr int RA = (TAPS == 3) ? 130 : 128;
    constexpr int RB = TAPS * 64;
    __shared__ unsigned short As[RA * 40];
    __shared__ unsigned short Bs[RB * 40];
    const int tid = threadIdx.x;
    const int w = tid >> 6, lane = tid & 63;
    const int g = lane >> 4, li = lane & 15;
    const int n0 = blockIdx.x * 64;
    const int m0 = blockIdx.y * 128;
    const int b = m0 >> 9, t0 = m0 & 511;
    const int len = lens[b];
    const unsigned short* Au = (const unsigned short*)A;
    const unsigned short* Wu = (const unsigned short*)W;

    f32x4 acc[2][4];
#pragma unroll
    for (int a = 0; a < 2; a++)
#pragma unroll
        for (int s = 0; s < 4; s++) acc[a][s] = (f32x4){0.f, 0.f, 0.f, 0.f};

#pragma unroll 1
    for (int k0 = 0; k0 < KC; k0 += 32) {
        __syncthreads();
        for (int c = tid; c < RA * 2; c += 256) {
            int i = c >> 1, hf = (c & 1) * 16;
            int t = t0 + i - (TAPS == 3 ? 1 : 0);
            bool valid = (t >= 0) && (t < NT);
            if constexpr (MODE == GM_CONV1) valid = valid && (t < len);
            short8 v0{}, v1{};
            if (valid) {
                const unsigned short* src = Au + ((size_t)(b * NT + t) * KC + k0 + hf);
                v0 = *(const short8*)src;
                v1 = *(const short8*)(src + 8);
            }
            *(short8*)&As[i * 40 + hf] = v0;
            *(short8*)&As[i * 40 + hf + 8] = v1;
        }
        for (int c = tid; c < RB * 4; c += 256) {
            int rb = c >> 2, qq = (c & 3) * 8;
            int dk = rb >> 6, nl = rb & 63;
            *(short8*)&Bs[rb * 40 + qq] =
                *(const short8*)(Wu + ((size_t)(dk * NTOT + n0 + nl) * KC + k0 + qq));
        }
        __syncthreads();
#pragma unroll
        for (int dk = 0; dk < TAPS; dk++) {
            short8 af0 = *(const short8*)&As[(w * 32 + li + dk) * 40 + g * 8];
            short8 af1 = *(const short8*)&As[(w * 32 + 16 + li + dk) * 40 + g * 8];
#pragma unroll
            for (int sub = 0; sub < 4; sub++) {
                short8 bfr = *(const short8*)&Bs[(dk * 64 + sub * 16 + li) * 40 + g * 8];
                acc[0][sub] = __builtin_amdgcn_mfma_f32_16x16x32_bf16(af0, bfr, acc[0][sub], 0, 0, 0);
                acc[1][sub] = __builtin_amdgcn_mfma_f32_16x16x32_bf16(af1, bfr, acc[1][sub], 0, 0, 0);
            }
        }
    }

#pragma unroll
    for (int sub = 0; sub < 4; sub++) {
        int n = n0 + sub * 16 + li;
        float bv = bias[n];
#pragma unroll
        for (int a = 0; a < 2; a++) {
#pragma unroll
            for (int rr = 0; rr < 4; rr++) {
                int t = t0 + w * 32 + a * 16 + g * 4 + rr;
                size_t m = (size_t)(b * NT + t);
                float vv = acc[a][sub][rr] + bv;
                if constexpr (MODE == GM_QKV) {
                    int iw = n / NC;
                    int cc = n - iw * NC;
                    int hh = cc >= NDH ? 1 : 0;
                    int d = cc - hh * NDH;
                    int bh = b * NHEAD + hh;
                    if (iw == 0) ob1[((size_t)bh * NT + t) * NDH + d] = __float2bfloat16(vv);
                    else if (iw == 1) ob2[((size_t)bh * NT + t) * NDH + d] = __float2bfloat16(vv);
                    else ob3[((size_t)bh * NDH + d) * NT + t] = __float2bfloat16(vv); // V^T
                } else if constexpr (MODE == GM_CONV1) {
                    vv = vv > 0.f ? vv : 0.f;
                    if (t >= len) vv = 0.f;
                    ob1[m * NDFF + n] = __float2bfloat16(vv);
                } else { // GM_PROJ
                    if (t >= len) vv = 0.f;
                    int half = n >= 192 ? 1 : 0;
                    int cc = n - half * 192;
                    of[(size_t)(half + 1) * MC + ((size_t)b * NC + cc) * NT + t] = vv;
                }
            }
        }
    }
}

// ---------------- fused GEMM + residual + LayerNorm (OPROJ / CONV2), M=128 ----------------
template <int KC, int TAPS, bool MASKY>
__global__ __launch_bounds__(256) void gemm_ln(const bf16* __restrict__ A,
                                               const bf16* __restrict__ W,
                                               const float* __restrict__ bias,
                                               const int* __restrict__ lens,
                                               const float* __restrict__ lng,
                                               const float* __restrict__ lnb,
                                               float* __restrict__ x,
                                               bf16* __restrict__ xb) {
    constexpr int RA = (TAPS == 3) ? 130 : 128;
    constexpr int RB = TAPS * 192;
    __shared__ unsigned short As[RA * 40];
    __shared__ unsigned short Bs[RB * 40];
    const int tid = threadIdx.x;
    const int w = tid >> 6, lane = tid & 63;
    const int g = lane >> 4, li = lane & 15;
    const int m0 = blockIdx.x * 128;
    const int b = m0 >> 9, t0 = m0 & 511;
    const int len = lens[b];
    const unsigned short* Au = (const unsigned short*)A;
    const unsigned short* Wu = (const unsigned short*)W;

    f32x4 acc[2][12];
#pragma unroll
    for (int a = 0; a < 2; a++)
#pragma unroll
        for (int s = 0; s < 12; s++) acc[a][s] = (f32x4){0.f, 0.f, 0.f, 0.f};

#pragma unroll 1
    for (int k0 = 0; k0 < KC; k0 += 32) {
        __syncthreads();
        for (int c = tid; c < RA * 2; c += 256) {
            int i = c >> 1, hf = (c & 1) * 16;
            int t = t0 + i - (TAPS == 3 ? 1 : 0);
            bool valid = (t >= 0) && (t < NT);
            short8 v0{}, v1{};
            if (valid) {
                const unsigned short* src = Au + ((size_t)(b * NT + t) * KC + k0 + hf);
                v0 = *(const short8*)src;
                v1 = *(const short8*)(src + 8);
            }
            *(short8*)&As[i * 40 + hf] = v0;
            *(short8*)&As[i * 40 + hf + 8] = v1;
        }
        for (int c = tid; c < RB * 4; c += 256) {
            int rb = c >> 2, qq = (c & 3) * 8;
            *(short8*)&Bs[rb * 40 + qq] = *(const short8*)(Wu + ((size_t)rb * KC + k0 + qq));
        }
        __syncthreads();
#pragma unroll
        for (int dk = 0; dk < TAPS; dk++) {
            short8 af0 = *(const short8*)&As[(w * 32 + li + dk) * 40 + g * 8];
            short8 af1 = *(const short8*)&As[(w * 32 + 16 + li + dk) * 40 + g * 8];
#pragma unroll
            for (int sub = 0; sub < 12; sub++) {
                short8 bfr = *(const short8*)&Bs[(dk * 192 + sub * 16 + li) * 40 + g * 8];
                acc[0][sub] = __builtin_amdgcn_mfma_f32_16x16x32_bf16(af0, bfr, acc[0][sub], 0, 0, 0);
                acc[1][sub] = __builtin_amdgcn_mfma_f32_16x16x32_bf16(af1, bfr, acc[1][sub], 0, 0, 0);
            }
        }
    }

    float biasv[12], gv[12], bbv[12];
#pragma unroll
    for (int sub = 0; sub < 12; sub++) {
        int n = sub * 16 + li;
        biasv[sub] = bias[n];
        gv[sub] = lng[n];
        bbv[sub] = lnb[n];
    }
#pragma unroll
    for (int a = 0; a < 2; a++) {
        float sm[4] = {0.f, 0.f, 0.f, 0.f}, sq[4] = {0.f, 0.f, 0.f, 0.f};
#pragma unroll
        for (int rr = 0; rr < 4; rr++) {
            int t = t0 + w * 32 + a * 16 + 4 * g + rr;
            size_t m = (size_t)(b * NT + t);
#pragma unroll
            for (int sub = 0; sub < 12; sub++) {
                float y = acc[a][sub][rr] + biasv[sub];
                if (MASKY && t >= len) y = 0.f;
                float r = y + x[m * NC + sub * 16 + li];
                acc[a][sub][rr] = r;
                sm[rr] += r;
                sq[rr] += r * r;
            }
        }
#pragma unroll
        for (int off = 1; off < 16; off <<= 1) {
#pragma unroll
            for (int rr = 0; rr < 4; rr++) {
                sm[rr] += __shfl_xor(sm[rr], off);
                sq[rr] += __shfl_xor(sq[rr], off);
            }
        }
#pragma unroll
        for (int rr = 0; rr < 4; rr++) {
            int t = t0 + w * 32 + a * 16 + 4 * g + rr;
            size_t m = (size_t)(b * NT + t);
            float mu = sm[rr] * (1.f / NC);
            float var = fmaxf(sq[rr] * (1.f / NC) - mu * mu, 0.f);
            float rs = rsqrtf(var + 1e-5f);
#pragma unroll
            for (int sub = 0; sub < 12; sub++) {
                float o = (acc[a][sub][rr] - mu) * rs * gv[sub] + bbv[sub];
                x[m * NC + sub * 16 + li] = o;
                xb[m * NC + sub * 16 + li] = __float2bfloat16(o);
            }
        }
    }
}

// ---------------- MFMA flash attention v4: q-tile 64, slim LDS (4 blocks/CU) ----------------
__global__ __launch_bounds__(256, 4) void attn_mfma(const bf16* __restrict__ q,
                                                    const bf16* __restrict__ k,
                                                    const bf16* __restrict__ v,
                                                    const float* __restrict__ relk,
                                                    const float* __restrict__ relv,
                                                    const int* __restrict__ lens,
                                                    bf16* __restrict__ o) {
    __shared__ __align__(16) char pool[40448];
    unsigned short* Kt = (unsigned short*)pool;              // [64][104]
    unsigned short* Vt = (unsigned short*)(pool + 13312);    // [96][72]
    unsigned short* Pt = (unsigned short*)(pool + 27136);    // [4][16][72]
    unsigned short* Pb = (unsigned short*)(pool + 36352);    // [4][16][32]
    unsigned short* Qt = (unsigned short*)pool;              // prologue alias [64][104]
    unsigned short* Rk = (unsigned short*)(pool + 13312);    // prologue alias [16][104]

    const int qt = blockIdx.x, bh = blockIdx.y;
    const int b = bh >> 1, h = bh & 1;
    const int q0 = qt * 64;
    const int tid = threadIdx.x;
    const int w = tid >> 6, lane = tid & 63;
    const int g = lane >> 4, li = lane & 15;
    const int len = lens[b];
    const float scale = 0.10206207261596575f; // 1/sqrt(96)

    const unsigned short* qg = (const unsigned short*)q + (size_t)bh * NT * NDH;
    const unsigned short* kg = (const unsigned short*)k + (size_t)bh * NT * NDH;
    const unsigned short* vg = (const unsigned short*)v + (size_t)bh * NDH * NT; // V^T [96][512]

    // ---- prologue ----
    for (int c = tid; c < 64 * 12; c += 256) {
        int r = c / 12, seg = (c % 12) * 8;
        *(short8*)&Qt[r * 104 + seg] = *(const short8*)(qg + (size_t)(q0 + r) * NDH + seg);
    }
    for (int c = tid; c < 16 * 96; c += 256) {
        int dd = c / 96, d = c - (c / 96) * 96;
        Rk[dd * 104 + d] = (dd < 9) ? f2b(relk[dd * 96 + d]) : (unsigned short)0;
    }
    for (int c = tid; c < 4 * 16 * 32; c += 256) Pb[c] = 0;
    __syncthreads();

    // racc = Rt rows (this wave's 16 q-rows): racc[rr] at lane (g,li) = Rt[4g+rr][li]
    f32x4 racc = (f32x4){0.f, 0.f, 0.f, 0.f};
    short8 qf[3];
#pragma unroll
    for (int kk = 0; kk < 3; kk++) {
        qf[kk] = *(const short8*)&Qt[(w * 16 + li) * 104 + kk * 32 + g * 8];
        short8 bfr = *(const short8*)&Rk[li * 104 + kk * 32 + g * 8];
        racc = __builtin_amdgcn_mfma_f32_16x16x32_bf16(qf[kk], bfr, racc, 0, 0, 0);
    }
    // rvf from global (only j<9 nonzero)
    short8 rvf[6];
#pragma unroll
    for (int ds = 0; ds < 6; ds++) {
#pragma unroll
        for (int i = 0; i < 8; i++) {
            int j = g * 8 + i;
            int d = ds * 16 + li;
            unsigned short u = (j < 9) ? f2b(relv[j * 96 + d]) : (unsigned short)0;
            rvf[ds][i] = (short)u;
        }
    }
    __syncthreads(); // Qt/Rk regions free

    float m_run[4], l_run[4];
    f32x4 Oa[6];
#pragma unroll
    for (int rr = 0; rr < 4; rr++) { m_run[rr] = -1e30f; l_run[rr] = 0.f; }
#pragma unroll
    for (int ds = 0; ds < 6; ds++) Oa[ds] = (f32x4){0.f, 0.f, 0.f, 0.f};

    for (int s0 = 0; s0 < NT; s0 += 64) {
        for (int c = tid; c < 64 * 12; c += 256) {
            int ss = c / 12, seg = (c % 12) * 8;
            *(short8*)&Kt[ss * 104 + seg] = *(const short8*)(kg + (size_t)(s0 + ss) * NDH + seg);
        }
        for (int c = tid; c < 96 * 8; c += 256) {
            int d = c >> 3, seg = (c & 7) * 8;
            *(short8*)&Vt[d * 72 + seg] = *(const short8*)(vg + (size_t)d * NT + s0 + seg);
        }
        __syncthreads();

        // ---- S = Q K^T ----
        f32x4 acc[4];
#pragma unroll
        for (int sub = 0; sub < 4; sub++) acc[sub] = (f32x4){0.f, 0.f, 0.f, 0.f};
        __builtin_amdgcn_s_setprio(1);
#pragma unroll
        for (int kk = 0; kk < 3; kk++) {
#pragma unroll
            for (int sub = 0; sub < 4; sub++) {
                short8 bfr = *(const short8*)&Kt[(sub * 16 + li) * 104 + kk * 32 + g * 8];
                acc[sub] = __builtin_amdgcn_mfma_f32_16x16x32_bf16(qf[kk], bfr, acc[sub], 0, 0, 0);
            }
        }
        __builtin_amdgcn_s_setprio(0);

        // ---- rel-K band (shfl from racc) + scale + mask + rowmax ----
        float rmax[4];
#pragma unroll
        for (int rr = 0; rr < 4; rr++) rmax[rr] = -1e30f;
#pragma unroll
        for (int sub = 0; sub < 4; sub++) {
#pragma unroll
            for (int rr = 0; rr < 4; rr++) {
                int scol = s0 + sub * 16 + li;
                int rloc = w * 16 + 4 * g + rr;
                int qrow = q0 + rloc;
                int dd = scol - qrow;
                float rv = __shfl(racc[rr], g * 16 + dd + NW);
                float val = acc[sub][rr];
                if (dd >= -NW && dd <= NW) val += rv;
                val *= scale;
                if (scol >= len || qrow >= len) val -= 10000.f;
                acc[sub][rr] = val;
                rmax[rr] = fmaxf(rmax[rr], val);
            }
        }
#pragma unroll
        for (int off = 1; off < 16; off <<= 1)
#pragma unroll
            for (int rr = 0; rr < 4; rr++) rmax[rr] = fmaxf(rmax[rr], __shfl_xor(rmax[rr], off));

        // ---- online softmax ----
        float scf[4];
#pragma unroll
        for (int rr = 0; rr < 4; rr++) {
            float mn = fmaxf(m_run[rr], rmax[rr]);
            scf[rr] = __expf(m_run[rr] - mn);
            m_run[rr] = mn;
        }
        float rsum[4] = {0.f, 0.f, 0.f, 0.f};
#pragma unroll
        for (int sub = 0; sub < 4; sub++)
#pragma unroll
            for (int rr = 0; rr < 4; rr++) {
                float p = __expf(acc[sub][rr] - m_run[rr]);
                acc[sub][rr] = p;
                rsum[rr] += p;
            }
#pragma unroll
        for (int off = 1; off < 16; off <<= 1)
#pragma unroll
            for (int rr = 0; rr < 4; rr++) rsum[rr] += __shfl_xor(rsum[rr], off);
#pragma unroll
        for (int rr = 0; rr < 4; rr++) l_run[rr] = l_run[rr] * scf[rr] + rsum[rr];
#pragma unroll
        for (int ds = 0; ds < 6; ds++)
#pragma unroll
            for (int rr = 0; rr < 4; rr++) Oa[ds][rr] *= scf[rr];

        // ---- P -> LDS (per-wave) ----
#pragma unroll
        for (int sub = 0; sub < 4; sub++)
#pragma unroll
            for (int rr = 0; rr < 4; rr++)
                Pt[w * 1152 + (4 * g + rr) * 72 + sub * 16 + li] = f2b(acc[sub][rr]);

        // ---- O += P V ----
        __builtin_amdgcn_s_setprio(1);
#pragma unroll
        for (int kk = 0; kk < 2; kk++) {
            short8 pa = *(const short8*)&Pt[w * 1152 + li * 72 + kk * 32 + g * 8];
#pragma unroll
            for (int ds = 0; ds < 6; ds++) {
                short8 bv = *(const short8*)&Vt[(ds * 16 + li) * 72 + kk * 32 + g * 8];
                Oa[ds] = __builtin_amdgcn_mfma_f32_16x16x32_bf16(pa, bv, Oa[ds], 0, 0, 0);
            }
        }
        __builtin_amdgcn_s_setprio(0);

        // ---- rel-V band via MFMA ----
        for (int c = lane; c < 144; c += 64) {
            int r = c / 9, j = c - (c / 9) * 9;
            int s = q0 + w * 16 + r + j - NW;
            unsigned short pv_ = 0;
            int u = s - s0;
            if (u >= 0 && u < 64) pv_ = Pt[w * 1152 + r * 72 + u];
            Pb[w * 512 + r * 32 + j] = pv_;
        }
        short8 pband = *(const short8*)&Pb[w * 512 + li * 32 + g * 8];
#pragma unroll
        for (int ds = 0; ds < 6; ds++)
            Oa[ds] = __builtin_amdgcn_mfma_f32_16x16x32_bf16(pband, rvf[ds], Oa[ds], 0, 0, 0);
        __syncthreads();
    }

    float invl[4];
#pragma unroll
    for (int rr = 0; rr < 4; rr++) invl[rr] = 1.f / l_run[rr];
#pragma unroll
    for (int ds = 0; ds < 6; ds++)
#pragma unroll
        for (int rr = 0; rr < 4; rr++) {
            int qrow = q0 + w * 16 + 4 * g + rr;
            o[((size_t)(b * NT + qrow)) * NC + h * 96 + ds * 16 + li] =
                __float2bfloat16(Oa[ds][rr] * invl[rr]);
        }
}

// ---------------- final x^T store (masked, f32) ----------------
__global__ __launch_bounds__(256) void xpose_kernel(const float* __restrict__ x,
                                                    const int* __restrict__ lens,
                                                    float* __restrict__ out) {
    int idx = blockIdx.x * 256 + threadIdx.x;
    if (idx >= (int)MC) return;
    int t = idx % NT;
    int bc = idx / NT;
    int c = bc % NC;
    int b = bc / NC;
    float v = (t < lens[b]) ? x[((size_t)b * NT + t) * NC + c] : 0.f;
    out[idx] = v;
}

__global__ __launch_bounds__(256) void mask_kernel(const int* __restrict__ lens, float* __restrict__ out) {
    int idx = blockIdx.x * 256 + threadIdx.x;
    if (idx >= NB * NT) return;
    int t = idx % NT;
    int b = idx / NT;
    out[idx] = (t < lens[b]) ? 1.f : 0.f;
}

extern "C" void kernel_launch(void* const* d_in, const int* in_sizes, int n_in,
                              void* d_out, int out_size, void* d_ws, size_t ws_size,
                              hipStream_t stream) {
    (void)in_sizes; (void)n_in; (void)out_size; (void)ws_size;
    const int* tok = (const int*)d_in[0];
    const int* lens = (const int*)d_in[1];
    const float* emb = (const float*)d_in[2];
    const float* wqkv = (const float*)d_in[3];
    const float* bqkv = (const float*)d_in[4];
    const float* wo = (const float*)d_in[5];
    const float* bo = (const float*)d_in[6];
    const float* relk = (const float*)d_in[7];
    const float* relv = (const float*)d_in[8];
    const float* ln1g = (const float*)d_in[9];
    const float* ln1b = (const float*)d_in[10];
    const float* ln2g = (const float*)d_in[11];
    const float* ln2b = (const float*)d_in[12];
    const float* fw1 = (const float*)d_in[13];
    const float* fb1 = (const float*)d_in[14];
    const float* fw2 = (const float*)d_in[15];
    const float* fb2 = (const float*)d_in[16];
    const float* pw = (const float*)d_in[17];
    const float* pb = (const float*)d_in[18];
    float* out = (float*)d_out;

    char* wsb = (char*)d_ws;
    float* xB = (float*)wsb;                       // f32 [M][C]
    bf16* xb = (bf16*)(wsb + 2 * MCB);             // bf16 [M][C]
    bf16* qb = (bf16*)(wsb + 2 * MCB + MCB / 2);   // bf16 [BH][T][DH]
    bf16* kb = qb + MC;
    bf16* vb = kb + MC;                            // stored transposed: [BH][DH][T]
    bf16* ob = vb + MC;
    bf16* hB = qb;                                 // alias: bf16 [M][DFF] over qb..ob
    bf16* pwqkv = ob + MC;
    bf16* pwo = pwqkv + (size_t)NLAYER * 3 * NC * NC;
    bf16* pw1 = pwo + (size_t)NLAYER * NC * NC;
    bf16* pw2 = pw1 + (size_t)NLAYER * 3 * NDFF * NC;
    bf16* pproj = pw2 + (size_t)NLAYER * 3 * NC * NDFF;

    {
        int n1 = NLAYER * 3 * NC * NC;
        cvt_plain<<<(n1 + 255) / 256, 256, 0, stream>>>(wqkv, pwqkv, n1);
        int n2 = NLAYER * NC * NC;
        cvt_plain<<<(n2 + 255) / 256, 256, 0, stream>>>(wo, pwo, n2);
        int n3 = 2 * 192 * NC;
        cvt_plain<<<(n3 + 255) / 256, 256, 0, stream>>>(pw, pproj, n3);
        int n4 = NLAYER * NDFF * NC * 3;
        cvt_conv<<<(n4 + 255) / 256, 256, 0, stream>>>(fw1, pw1, NLAYER, NDFF, NC);
        int n5 = NLAYER * NC * NDFF * 3;
        cvt_conv<<<(n5 + 255) / 256, 256, 0, stream>>>(fw2, pw2, NLAYER, NC, NDFF);
    }

    embed_kernel<<<(int)((MC + 255) / 256), 256, 0, stream>>>(tok, lens, emb, xB, xb);

    for (int l = 0; l < NLAYER; l++) {
        gemm_mfma<GM_QKV, 576, 192, 1><<<dim3(9, 256), 256, 0, stream>>>(
            xb, pwqkv + (size_t)l * 3 * NC * NC, bqkv + (size_t)l * 3 * NC, lens,
            nullptr, qb, kb, vb);
        attn_mfma<<<dim3(8, NB * NHEAD), 256, 0, stream>>>(
            qb, kb, vb, relk + (size_t)l * (2 * NW + 1) * NDH,
            relv + (size_t)l * (2 * NW + 1) * NDH, lens, ob);
        gemm_ln<192, 1, false><<<256, 256, 0, stream>>>(
            ob, pwo + (size_t)l * NC * NC, bo + (size_t)l * NC, lens,
            ln1g + (size_t)l * NC, ln1b + (size_t)l * NC, xB, xb);
        gemm_mfma<GM_CONV1, 768, 192, 3><<<dim3(12, 256), 256, 0, stream>>>(
            xb, pw1 + (size_t)l * 3 * NDFF * NC, fb1 + (size_t)l * NDFF, lens,
            nullptr, hB, nullptr, nullptr);
        gemm_ln<768, 3, true><<<256, 256, 0, stream>>>(
            hB, pw2 + (size_t)l * 3 * NC * NDFF, fb2 + (size_t)l * NC, lens,
            ln2g + (size_t)l * NC, ln2b + (size_t)l * NC, xB, xb);
    }

    gemm_mfma<GM_PROJ, 384, 192, 1><<<dim3(6, 256), 256, 0, stream>>>(
        xb, pproj, pb, lens, out, nullptr, nullptr, nullptr);
    xpose_kernel<<<(int)((MC + 255) / 256), 256, 0, stream>>>(xB, lens, out);
    mask_kernel<<<(NB * NT + 255) / 256, 256, 0, stream>>>(lens, out + 3 * MC);
}

// Round 8
// 1538.855 us; speedup vs baseline: 12.2095x; 1.1343x over previous
//
#include <hip/hip_runtime.h>
#include <hip/hip_bf16.h>

typedef __hip_bfloat16 bf16;
typedef __attribute__((ext_vector_type(8))) short short8;
typedef __attribute__((ext_vector_type(4))) float f32x4;

#define NB 64
#define NT 512
#define NC 192
#define NHEAD 2
#define NDH 96
#define NLAYER 6
#define NDFF 768
#define NW 4

constexpr int MROWS = NB * NT;            // 32768
constexpr size_t MC = (size_t)MROWS * NC; // 6291456
constexpr size_t MCB = MC * 4;

__device__ __forceinline__ float us2f(unsigned short x) { return __uint_as_float((unsigned)x << 16); }
__device__ __forceinline__ unsigned short f2b(float f) {
    bf16 h = __float2bfloat16(f);
    return *reinterpret_cast<unsigned short*>(&h);
}

// ---------------- weight conversion ----------------
__global__ __launch_bounds__(256) void cvt_plain(const float* __restrict__ s, bf16* __restrict__ d, int n) {
    int i = blockIdx.x * 256 + threadIdx.x;
    if (i < n) d[i] = __float2bfloat16(s[i]);
}
// [L][N][C][3] f32 -> [L][3][N][C] bf16
__global__ __launch_bounds__(256) void cvt_conv(const float* __restrict__ s, bf16* __restrict__ d,
                                                int L, int N, int C) {
    int i = blockIdx.x * 256 + threadIdx.x;
    if (i >= L * N * C * 3) return;
    int dk = i % 3;
    int rest = i / 3;
    int c = rest % C;
    int rest2 = rest / C;
    int n = rest2 % N;
    int l = rest2 / N;
    d[(((size_t)l * 3 + dk) * N + n) * C + c] = __float2bfloat16(s[i]);
}

// ---------------- embedding ----------------
__global__ __launch_bounds__(256) void embed_kernel(const int* __restrict__ tok,
                                                    const int* __restrict__ lens,
                                                    const float* __restrict__ emb,
                                                    float* __restrict__ x,
                                                    bf16* __restrict__ xb) {
    int idx = blockIdx.x * 256 + threadIdx.x;
    if (idx >= (int)MC) return;
    int c = idx % NC;
    int m = idx / NC;
    int t = m % NT, b = m / NT;
    float v = emb[tok[m] * NC + c] * 13.856406460551018f; // sqrt(192)
    if (t >= lens[b]) v = 0.f;
    x[idx] = v;
    xb[idx] = __float2bfloat16(v);
}

// ---------------- plain MFMA GEMM (QKV / CONV1 / PROJ), tap-folded ----------------
enum GMode { GM_QKV = 0, GM_CONV1 = 2, GM_PROJ = 4 };

template <int MODE, int NTOT, int KC, int TAPS>
__global__ __launch_bounds__(256) void gemm_mfma(const bf16* __restrict__ A,
                                                 const bf16* __restrict__ W,
                                                 const float* __restrict__ bias,
                                                 const int* __restrict__ lens,
                                                 float* __restrict__ of,
                                                 bf16* __restrict__ ob1,
                                                 bf16* __restrict__ ob2,
                                                 bf16* __restrict__ ob3) {
    constexpr int RA = (TAPS == 3) ? 130 : 128;
    constexpr int RB = TAPS * 64;
    __shared__ unsigned short As[RA * 40];
    __shared__ unsigned short Bs[RB * 40];
    const int tid = threadIdx.x;
    const int w = tid >> 6, lane = tid & 63;
    const int g = lane >> 4, li = lane & 15;
    const int n0 = blockIdx.x * 64;
    const int m0 = blockIdx.y * 128;
    const int b = m0 >> 9, t0 = m0 & 511;
    const int len = lens[b];
    const unsigned short* Au = (const unsigned short*)A;
    const unsigned short* Wu = (const unsigned short*)W;

    f32x4 acc[2][4];
#pragma unroll
    for (int a = 0; a < 2; a++)
#pragma unroll
        for (int s = 0; s < 4; s++) acc[a][s] = (f32x4){0.f, 0.f, 0.f, 0.f};

#pragma unroll 1
    for (int k0 = 0; k0 < KC; k0 += 32) {
        __syncthreads();
        for (int c = tid; c < RA * 2; c += 256) {
            int i = c >> 1, hf = (c & 1) * 16;
            int t = t0 + i - (TAPS == 3 ? 1 : 0);
            bool valid = (t >= 0) && (t < NT);
            if constexpr (MODE == GM_CONV1) valid = valid && (t < len);
            short8 v0{}, v1{};
            if (valid) {
                const unsigned short* src = Au + ((size_t)(b * NT + t) * KC + k0 + hf);
                v0 = *(const short8*)src;
                v1 = *(const short8*)(src + 8);
            }
            *(short8*)&As[i * 40 + hf] = v0;
            *(short8*)&As[i * 40 + hf + 8] = v1;
        }
        for (int c = tid; c < RB * 4; c += 256) {
            int rb = c >> 2, qq = (c & 3) * 8;
            int dk = rb >> 6, nl = rb & 63;
            *(short8*)&Bs[rb * 40 + qq] =
                *(const short8*)(Wu + ((size_t)(dk * NTOT + n0 + nl) * KC + k0 + qq));
        }
        __syncthreads();
#pragma unroll
        for (int dk = 0; dk < TAPS; dk++) {
            short8 af0 = *(const short8*)&As[(w * 32 + li + dk) * 40 + g * 8];
            short8 af1 = *(const short8*)&As[(w * 32 + 16 + li + dk) * 40 + g * 8];
#pragma unroll
            for (int sub = 0; sub < 4; sub++) {
                short8 bfr = *(const short8*)&Bs[(dk * 64 + sub * 16 + li) * 40 + g * 8];
                acc[0][sub] = __builtin_amdgcn_mfma_f32_16x16x32_bf16(af0, bfr, acc[0][sub], 0, 0, 0);
                acc[1][sub] = __builtin_amdgcn_mfma_f32_16x16x32_bf16(af1, bfr, acc[1][sub], 0, 0, 0);
            }
        }
    }

#pragma unroll
    for (int sub = 0; sub < 4; sub++) {
        int n = n0 + sub * 16 + li;
        float bv = bias[n];
#pragma unroll
        for (int a = 0; a < 2; a++) {
#pragma unroll
            for (int rr = 0; rr < 4; rr++) {
                int t = t0 + w * 32 + a * 16 + g * 4 + rr;
                size_t m = (size_t)(b * NT + t);
                float vv = acc[a][sub][rr] + bv;
                if constexpr (MODE == GM_QKV) {
                    int iw = n / NC;
                    int cc = n - iw * NC;
                    int hh = cc >= NDH ? 1 : 0;
                    int d = cc - hh * NDH;
                    int bh = b * NHEAD + hh;
                    if (iw == 0) ob1[((size_t)bh * NT + t) * NDH + d] = __float2bfloat16(vv);
                    else if (iw == 1) ob2[((size_t)bh * NT + t) * NDH + d] = __float2bfloat16(vv);
                    else ob3[((size_t)bh * NDH + d) * NT + t] = __float2bfloat16(vv); // V^T
                } else if constexpr (MODE == GM_CONV1) {
                    vv = vv > 0.f ? vv : 0.f;
                    if (t >= len) vv = 0.f;
                    ob1[m * NDFF + n] = __float2bfloat16(vv);
                } else { // GM_PROJ
                    if (t >= len) vv = 0.f;
                    int half = n >= 192 ? 1 : 0;
                    int cc = n - half * 192;
                    of[(size_t)(half + 1) * MC + ((size_t)b * NC + cc) * NT + t] = vv;
                }
            }
        }
    }
}

// ---------------- fused GEMM + residual + LayerNorm (OPROJ / CONV2) ----------------
// 512 threads, 8 waves as 2 (row-half) x 4 (col-group); wave = 64 rows x 48 cols.
// Reg double-buffered staging: load k+1 into regs before compute of k, LDS write after barrier.
template <int KC, int TAPS, bool MASKY>
__global__ __launch_bounds__(512) void gemm_ln(const bf16* __restrict__ A,
                                               const bf16* __restrict__ W,
                                               const float* __restrict__ bias,
                                               const int* __restrict__ lens,
                                               const float* __restrict__ lng,
                                               const float* __restrict__ lnb,
                                               float* __restrict__ x,
                                               bf16* __restrict__ xb) {
    constexpr int RA = (TAPS == 3) ? 130 : 128;
    constexpr int RB = TAPS * 192;
    constexpr int NSTEP = KC / 32;
    constexpr int NBI = (RB * 4 + 511) / 512;
    __shared__ unsigned short As[RA * 40];
    __shared__ unsigned short Bs[RB * 40];
    __shared__ float rsm[128][4];
    __shared__ float rsq[128][4];
    const int tid = threadIdx.x;
    const int lane = tid & 63;
    const int g = lane >> 4, li = lane & 15;
    const int w = tid >> 6;
    const int wr = w & 1, wc = w >> 1;    // wr: row half, wc: col group (48 cols)
    const int m0 = blockIdx.x * 128;
    const int b = m0 >> 9, t0 = m0 & 511;
    const int len = lens[b];
    const unsigned short* Au = (const unsigned short*)A;
    const unsigned short* Wu = (const unsigned short*)W;

    // fixed staging coordinates
    const int ai = tid >> 1, ahf = (tid & 1) * 16;
    const int at = t0 + ai - (TAPS == 3 ? 1 : 0);
    const bool aon = (tid < RA * 2);
    const bool avalid = aon && (at >= 0) && (at < NT);

    short8 ra0{}, ra1{};
    short8 rbv[NBI];
#pragma unroll
    for (int j = 0; j < NBI; j++) rbv[j] = short8{};

    f32x4 acc[4][3];
#pragma unroll
    for (int ar = 0; ar < 4; ar++)
#pragma unroll
        for (int sub = 0; sub < 3; sub++) acc[ar][sub] = (f32x4){0.f, 0.f, 0.f, 0.f};

    // ---- prologue: load + write step 0 ----
    if (avalid) {
        const unsigned short* src = Au + ((size_t)(b * NT + at) * KC + 0 + ahf);
        ra0 = *(const short8*)src;
        ra1 = *(const short8*)(src + 8);
    }
#pragma unroll
    for (int j = 0; j < NBI; j++) {
        int cb = tid + j * 512;
        if (cb < RB * 4) {
            int rbr = cb >> 2, qq = (cb & 3) * 8;
            rbv[j] = *(const short8*)(Wu + ((size_t)rbr * KC + 0 + qq));
        }
    }
    if (aon) {
        short8 z{};
        *(short8*)&As[ai * 40 + ahf] = avalid ? ra0 : z;
        *(short8*)&As[ai * 40 + ahf + 8] = avalid ? ra1 : z;
    }
#pragma unroll
    for (int j = 0; j < NBI; j++) {
        int cb = tid + j * 512;
        if (cb < RB * 4) {
            int rbr = cb >> 2, qq = (cb & 3) * 8;
            *(short8*)&Bs[rbr * 40 + qq] = rbv[j];
        }
    }

#pragma unroll 1
    for (int s = 0; s < NSTEP; s++) {
        __syncthreads();
        // issue next step's global loads (latency hides under compute)
        if (s + 1 < NSTEP) {
            int k0 = (s + 1) * 32;
            if (avalid) {
                const unsigned short* src = Au + ((size_t)(b * NT + at) * KC + k0 + ahf);
                ra0 = *(const short8*)src;
                ra1 = *(const short8*)(src + 8);
            }
#pragma unroll
            for (int j = 0; j < NBI; j++) {
                int cb = tid + j * 512;
                if (cb < RB * 4) {
                    int rbr = cb >> 2, qq = (cb & 3) * 8;
                    rbv[j] = *(const short8*)(Wu + ((size_t)rbr * KC + k0 + qq));
                }
            }
        }
        // compute from LDS
#pragma unroll
        for (int dk = 0; dk < TAPS; dk++) {
            short8 af[4];
#pragma unroll
            for (int ar = 0; ar < 4; ar++)
                af[ar] = *(const short8*)&As[(wr * 64 + ar * 16 + li + dk) * 40 + g * 8];
#pragma unroll
            for (int sub = 0; sub < 3; sub++) {
                short8 bfr = *(const short8*)&Bs[(dk * 192 + wc * 48 + sub * 16 + li) * 40 + g * 8];
#pragma unroll
                for (int ar = 0; ar < 4; ar++)
                    acc[ar][sub] = __builtin_amdgcn_mfma_f32_16x16x32_bf16(af[ar], bfr, acc[ar][sub], 0, 0, 0);
            }
        }
        __syncthreads();
        if (s + 1 < NSTEP) {
            if (aon) {
                short8 z{};
                *(short8*)&As[ai * 40 + ahf] = avalid ? ra0 : z;
                *(short8*)&As[ai * 40 + ahf + 8] = avalid ? ra1 : z;
            }
#pragma unroll
            for (int j = 0; j < NBI; j++) {
                int cb = tid + j * 512;
                if (cb < RB * 4) {
                    int rbr = cb >> 2, qq = (cb & 3) * 8;
                    *(short8*)&Bs[rbr * 40 + qq] = rbv[j];
                }
            }
        }
    }

    // ---- epilogue: bias + (mask) + residual, then row LN across col-groups ----
    float biasv[3], gv[3], bbv[3];
#pragma unroll
    for (int sub = 0; sub < 3; sub++) {
        int n = wc * 48 + sub * 16 + li;
        biasv[sub] = bias[n];
        gv[sub] = lng[n];
        bbv[sub] = lnb[n];
    }
    float psm[4][4], psq[4][4];
#pragma unroll
    for (int ar = 0; ar < 4; ar++) {
#pragma unroll
        for (int rr = 0; rr < 4; rr++) {
            int r = wr * 64 + ar * 16 + 4 * g + rr;
            int t = t0 + r;
            size_t m = (size_t)(b * NT + t);
            float sm = 0.f, sq = 0.f;
#pragma unroll
            for (int sub = 0; sub < 3; sub++) {
                int n = wc * 48 + sub * 16 + li;
                float y = acc[ar][sub][rr] + biasv[sub];
                if (MASKY && t >= len) y = 0.f;
                float rres = y + x[m * NC + n];
                acc[ar][sub][rr] = rres;
                sm += rres;
                sq += rres * rres;
            }
            psm[ar][rr] = sm;
            psq[ar][rr] = sq;
        }
    }
#pragma unroll
    for (int off = 1; off < 16; off <<= 1) {
#pragma unroll
        for (int ar = 0; ar < 4; ar++)
#pragma unroll
            for (int rr = 0; rr < 4; rr++) {
                psm[ar][rr] += __shfl_xor(psm[ar][rr], off);
                psq[ar][rr] += __shfl_xor(psq[ar][rr], off);
            }
    }
    if (li == 0) {
#pragma unroll
        for (int ar = 0; ar < 4; ar++)
#pragma unroll
            for (int rr = 0; rr < 4; rr++) {
                int r = wr * 64 + ar * 16 + 4 * g + rr;
                rsm[r][wc] = psm[ar][rr];
                rsq[r][wc] = psq[ar][rr];
            }
    }
    __syncthreads();
#pragma unroll
    for (int ar = 0; ar < 4; ar++) {
#pragma unroll
        for (int rr = 0; rr < 4; rr++) {
            int r = wr * 64 + ar * 16 + 4 * g + rr;
            int t = t0 + r;
            size_t m = (size_t)(b * NT + t);
            float sm = rsm[r][0] + rsm[r][1] + rsm[r][2] + rsm[r][3];
            float sq = rsq[r][0] + rsq[r][1] + rsq[r][2] + rsq[r][3];
            float mu = sm * (1.f / NC);
            float var = fmaxf(sq * (1.f / NC) - mu * mu, 0.f);
            float rs = rsqrtf(var + 1e-5f);
#pragma unroll
            for (int sub = 0; sub < 3; sub++) {
                int n = wc * 48 + sub * 16 + li;
                float o = (acc[ar][sub][rr] - mu) * rs * gv[sub] + bbv[sub];
                x[m * NC + n] = o;
                xb[m * NC + n] = __float2bfloat16(o);
            }
        }
    }
}

// ---------------- MFMA flash attention v4: q-tile 64, slim LDS (4 blocks/CU) ----------------
__global__ __launch_bounds__(256, 4) void attn_mfma(const bf16* __restrict__ q,
                                                    const bf16* __restrict__ k,
                                                    const bf16* __restrict__ v,
                                                    const float* __restrict__ relk,
                                                    const float* __restrict__ relv,
                                                    const int* __restrict__ lens,
                                                    bf16* __restrict__ o) {
    __shared__ __align__(16) char pool[40448];
    unsigned short* Kt = (unsigned short*)pool;              // [64][104]
    unsigned short* Vt = (unsigned short*)(pool + 13312);    // [96][72]
    unsigned short* Pt = (unsigned short*)(pool + 27136);    // [4][16][72]
    unsigned short* Pb = (unsigned short*)(pool + 36352);    // [4][16][32]
    unsigned short* Qt = (unsigned short*)pool;              // prologue alias [64][104]
    unsigned short* Rk = (unsigned short*)(pool + 13312);    // prologue alias [16][104]

    const int qt = blockIdx.x, bh = blockIdx.y;
    const int b = bh >> 1, h = bh & 1;
    const int q0 = qt * 64;
    const int tid = threadIdx.x;
    const int w = tid >> 6, lane = tid & 63;
    const int g = lane >> 4, li = lane & 15;
    const int len = lens[b];
    const float scale = 0.10206207261596575f; // 1/sqrt(96)

    const unsigned short* qg = (const unsigned short*)q + (size_t)bh * NT * NDH;
    const unsigned short* kg = (const unsigned short*)k + (size_t)bh * NT * NDH;
    const unsigned short* vg = (const unsigned short*)v + (size_t)bh * NDH * NT; // V^T [96][512]

    // ---- prologue ----
    for (int c = tid; c < 64 * 12; c += 256) {
        int r = c / 12, seg = (c % 12) * 8;
        *(short8*)&Qt[r * 104 + seg] = *(const short8*)(qg + (size_t)(q0 + r) * NDH + seg);
    }
    for (int c = tid; c < 16 * 96; c += 256) {
        int dd = c / 96, d = c - (c / 96) * 96;
        Rk[dd * 104 + d] = (dd < 9) ? f2b(relk[dd * 96 + d]) : (unsigned short)0;
    }
    for (int c = tid; c < 4 * 16 * 32; c += 256) Pb[c] = 0;
    __syncthreads();

    // racc = Rt rows (this wave's 16 q-rows): racc[rr] at lane (g,li) = Rt[4g+rr][li]
    f32x4 racc = (f32x4){0.f, 0.f, 0.f, 0.f};
    short8 qf[3];
#pragma unroll
    for (int kk = 0; kk < 3; kk++) {
        qf[kk] = *(const short8*)&Qt[(w * 16 + li) * 104 + kk * 32 + g * 8];
        short8 bfr = *(const short8*)&Rk[li * 104 + kk * 32 + g * 8];
        racc = __builtin_amdgcn_mfma_f32_16x16x32_bf16(qf[kk], bfr, racc, 0, 0, 0);
    }
    // rvf from global (only j<9 nonzero)
    short8 rvf[6];
#pragma unroll
    for (int ds = 0; ds < 6; ds++) {
#pragma unroll
        for (int i = 0; i < 8; i++) {
            int j = g * 8 + i;
            int d = ds * 16 + li;
            unsigned short u = (j < 9) ? f2b(relv[j * 96 + d]) : (unsigned short)0;
            rvf[ds][i] = (short)u;
        }
    }
    __syncthreads(); // Qt/Rk regions free

    float m_run[4], l_run[4];
    f32x4 Oa[6];
#pragma unroll
    for (int rr = 0; rr < 4; rr++) { m_run[rr] = -1e30f; l_run[rr] = 0.f; }
#pragma unroll
    for (int ds = 0; ds < 6; ds++) Oa[ds] = (f32x4){0.f, 0.f, 0.f, 0.f};

    for (int s0 = 0; s0 < NT; s0 += 64) {
        for (int c = tid; c < 64 * 12; c += 256) {
            int ss = c / 12, seg = (c % 12) * 8;
            *(short8*)&Kt[ss * 104 + seg] = *(const short8*)(kg + (size_t)(s0 + ss) * NDH + seg);
        }
        for (int c = tid; c < 96 * 8; c += 256) {
            int d = c >> 3, seg = (c & 7) * 8;
            *(short8*)&Vt[d * 72 + seg] = *(const short8*)(vg + (size_t)d * NT + s0 + seg);
        }
        __syncthreads();

        // ---- S = Q K^T ----
        f32x4 acc[4];
#pragma unroll
        for (int sub = 0; sub < 4; sub++) acc[sub] = (f32x4){0.f, 0.f, 0.f, 0.f};
        __builtin_amdgcn_s_setprio(1);
#pragma unroll
        for (int kk = 0; kk < 3; kk++) {
#pragma unroll
            for (int sub = 0; sub < 4; sub++) {
                short8 bfr = *(const short8*)&Kt[(sub * 16 + li) * 104 + kk * 32 + g * 8];
                acc[sub] = __builtin_amdgcn_mfma_f32_16x16x32_bf16(qf[kk], bfr, acc[sub], 0, 0, 0);
            }
        }
        __builtin_amdgcn_s_setprio(0);

        // ---- rel-K band (shfl from racc) + scale + mask + rowmax ----
        float rmax[4];
#pragma unroll
        for (int rr = 0; rr < 4; rr++) rmax[rr] = -1e30f;
#pragma unroll
        for (int sub = 0; sub < 4; sub++) {
#pragma unroll
            for (int rr = 0; rr < 4; rr++) {
                int scol = s0 + sub * 16 + li;
                int rloc = w * 16 + 4 * g + rr;
                int qrow = q0 + rloc;
                int dd = scol - qrow;
                float rv = __shfl(racc[rr], g * 16 + dd + NW);
                float val = acc[sub][rr];
                if (dd >= -NW && dd <= NW) val += rv;
                val *= scale;
                if (scol >= len || qrow >= len) val -= 10000.f;
                acc[sub][rr] = val;
                rmax[rr] = fmaxf(rmax[rr], val);
            }
        }
#pragma unroll
        for (int off = 1; off < 16; off <<= 1)
#pragma unroll
            for (int rr = 0; rr < 4; rr++) rmax[rr] = fmaxf(rmax[rr], __shfl_xor(rmax[rr], off));

        // ---- online softmax ----
        float scf[4];
#pragma unroll
        for (int rr = 0; rr < 4; rr++) {
            float mn = fmaxf(m_run[rr], rmax[rr]);
            scf[rr] = __expf(m_run[rr] - mn);
            m_run[rr] = mn;
        }
        float rsum[4] = {0.f, 0.f, 0.f, 0.f};
#pragma unroll
        for (int sub = 0; sub < 4; sub++)
#pragma unroll
            for (int rr = 0; rr < 4; rr++) {
                float p = __expf(acc[sub][rr] - m_run[rr]);
                acc[sub][rr] = p;
                rsum[rr] += p;
            }
#pragma unroll
        for (int off = 1; off < 16; off <<= 1)
#pragma unroll
            for (int rr = 0; rr < 4; rr++) rsum[rr] += __shfl_xor(rsum[rr], off);
#pragma unroll
        for (int rr = 0; rr < 4; rr++) l_run[rr] = l_run[rr] * scf[rr] + rsum[rr];
#pragma unroll
        for (int ds = 0; ds < 6; ds++)
#pragma unroll
            for (int rr = 0; rr < 4; rr++) Oa[ds][rr] *= scf[rr];

        // ---- P -> LDS (per-wave) ----
#pragma unroll
        for (int sub = 0; sub < 4; sub++)
#pragma unroll
            for (int rr = 0; rr < 4; rr++)
                Pt[w * 1152 + (4 * g + rr) * 72 + sub * 16 + li] = f2b(acc[sub][rr]);

        // ---- O += P V ----
        __builtin_amdgcn_s_setprio(1);
#pragma unroll
        for (int kk = 0; kk < 2; kk++) {
            short8 pa = *(const short8*)&Pt[w * 1152 + li * 72 + kk * 32 + g * 8];
#pragma unroll
            for (int ds = 0; ds < 6; ds++) {
                short8 bv = *(const short8*)&Vt[(ds * 16 + li) * 72 + kk * 32 + g * 8];
                Oa[ds] = __builtin_amdgcn_mfma_f32_16x16x32_bf16(pa, bv, Oa[ds], 0, 0, 0);
            }
        }
        __builtin_amdgcn_s_setprio(0);

        // ---- rel-V band via MFMA ----
        for (int c = lane; c < 144; c += 64) {
            int r = c / 9, j = c - (c / 9) * 9;
            int s = q0 + w * 16 + r + j - NW;
            unsigned short pv_ = 0;
            int u = s - s0;
            if (u >= 0 && u < 64) pv_ = Pt[w * 1152 + r * 72 + u];
            Pb[w * 512 + r * 32 + j] = pv_;
        }
        short8 pband = *(const short8*)&Pb[w * 512 + li * 32 + g * 8];
#pragma unroll
        for (int ds = 0; ds < 6; ds++)
            Oa[ds] = __builtin_amdgcn_mfma_f32_16x16x32_bf16(pband, rvf[ds], Oa[ds], 0, 0, 0);
        __syncthreads();
    }

    float invl[4];
#pragma unroll
    for (int rr = 0; rr < 4; rr++) invl[rr] = 1.f / l_run[rr];
#pragma unroll
    for (int ds = 0; ds < 6; ds++)
#pragma unroll
        for (int rr = 0; rr < 4; rr++) {
            int qrow = q0 + w * 16 + 4 * g + rr;
            o[((size_t)(b * NT + qrow)) * NC + h * 96 + ds * 16 + li] =
                __float2bfloat16(Oa[ds][rr] * invl[rr]);
        }
}

// ---------------- final x^T store (masked, f32) ----------------
__global__ __launch_bounds__(256) void xpose_kernel(const float* __restrict__ x,
                                                    const int* __restrict__ lens,
                                                    float* __restrict__ out) {
    int idx = blockIdx.x * 256 + threadIdx.x;
    if (idx >= (int)MC) return;
    int t = idx % NT;
    int bc = idx / NT;
    int c = bc % NC;
    int b = bc / NC;
    float v = (t < lens[b]) ? x[((size_t)b * NT + t) * NC + c] : 0.f;
    out[idx] = v;
}

__global__ __launch_bounds__(256) void mask_kernel(const int* __restrict__ lens, float* __restrict__ out) {
    int idx = blockIdx.x * 256 + threadIdx.x;
    if (idx >= NB * NT) return;
    int t = idx % NT;
    int b = idx / NT;
    out[idx] = (t < lens[b]) ? 1.f : 0.f;
}

extern "C" void kernel_launch(void* const* d_in, const int* in_sizes, int n_in,
                              void* d_out, int out_size, void* d_ws, size_t ws_size,
                              hipStream_t stream) {
    (void)in_sizes; (void)n_in; (void)out_size; (void)ws_size;
    const int* tok = (const int*)d_in[0];
    const int* lens = (const int*)d_in[1];
    const float* emb = (const float*)d_in[2];
    const float* wqkv = (const float*)d_in[3];
    const float* bqkv = (const float*)d_in[4];
    const float* wo = (const float*)d_in[5];
    const float* bo = (const float*)d_in[6];
    const float* relk = (const float*)d_in[7];
    const float* relv = (const float*)d_in[8];
    const float* ln1g = (const float*)d_in[9];
    const float* ln1b = (const float*)d_in[10];
    const float* ln2g = (const float*)d_in[11];
    const float* ln2b = (const float*)d_in[12];
    const float* fw1 = (const float*)d_in[13];
    const float* fb1 = (const float*)d_in[14];
    const float* fw2 = (const float*)d_in[15];
    const float* fb2 = (const float*)d_in[16];
    const float* pw = (const float*)d_in[17];
    const float* pb = (const float*)d_in[18];
    float* out = (float*)d_out;

    char* wsb = (char*)d_ws;
    float* xB = (float*)wsb;                       // f32 [M][C]
    bf16* xb = (bf16*)(wsb + 2 * MCB);             // bf16 [M][C]
    bf16* qb = (bf16*)(wsb + 2 * MCB + MCB / 2);   // bf16 [BH][T][DH]
    bf16* kb = qb + MC;
    bf16* vb = kb + MC;                            // stored transposed: [BH][DH][T]
    bf16* ob = vb + MC;
    bf16* hB = qb;                                 // alias: bf16 [M][DFF] over qb..ob
    bf16* pwqkv = ob + MC;
    bf16* pwo = pwqkv + (size_t)NLAYER * 3 * NC * NC;
    bf16* pw1 = pwo + (size_t)NLAYER * NC * NC;
    bf16* pw2 = pw1 + (size_t)NLAYER * 3 * NDFF * NC;
    bf16* pproj = pw2 + (size_t)NLAYER * 3 * NC * NDFF;

    {
        int n1 = NLAYER * 3 * NC * NC;
        cvt_plain<<<(n1 + 255) / 256, 256, 0, stream>>>(wqkv, pwqkv, n1);
        int n2 = NLAYER * NC * NC;
        cvt_plain<<<(n2 + 255) / 256, 256, 0, stream>>>(wo, pwo, n2);
        int n3 = 2 * 192 * NC;
        cvt_plain<<<(n3 + 255) / 256, 256, 0, stream>>>(pw, pproj, n3);
        int n4 = NLAYER * NDFF * NC * 3;
        cvt_conv<<<(n4 + 255) / 256, 256, 0, stream>>>(fw1, pw1, NLAYER, NDFF, NC);
        int n5 = NLAYER * NC * NDFF * 3;
        cvt_conv<<<(n5 + 255) / 256, 256, 0, stream>>>(fw2, pw2, NLAYER, NC, NDFF);
    }

    embed_kernel<<<(int)((MC + 255) / 256), 256, 0, stream>>>(tok, lens, emb, xB, xb);

    for (int l = 0; l < NLAYER; l++) {
        gemm_mfma<GM_QKV, 576, 192, 1><<<dim3(9, 256), 256, 0, stream>>>(
            xb, pwqkv + (size_t)l * 3 * NC * NC, bqkv + (size_t)l * 3 * NC, lens,
            nullptr, qb, kb, vb);
        attn_mfma<<<dim3(8, NB * NHEAD), 256, 0, stream>>>(
            qb, kb, vb, relk + (size_t)l * (2 * NW + 1) * NDH,
            relv + (size_t)l * (2 * NW + 1) * NDH, lens, ob);
        gemm_ln<192, 1, false><<<256, 512, 0, stream>>>(
            ob, pwo + (size_t)l * NC * NC, bo + (size_t)l * NC, lens,
            ln1g + (size_t)l * NC, ln1b + (size_t)l * NC, xB, xb);
        gemm_mfma<GM_CONV1, 768, 192, 3><<<dim3(12, 256), 256, 0, stream>>>(
            xb, pw1 + (size_t)l * 3 * NDFF * NC, fb1 + (size_t)l * NDFF, lens,
            nullptr, hB, nullptr, nullptr);
        gemm_ln<768, 3, true><<<256, 512, 0, stream>>>(
            hB, pw2 + (size_t)l * 3 * NC * NDFF, fb2 + (size_t)l * NC, lens,
            ln2g + (size_t)l * NC, ln2b + (size_t)l * NC, xB, xb);
    }

    gemm_mfma<GM_PROJ, 384, 192, 1><<<dim3(6, 256), 256, 0, stream>>>(
        xb, pproj, pb, lens, out, nullptr, nullptr, nullptr);
    xpose_kernel<<<(int)((MC + 255) / 256), 256, 0, stream>>>(xB, lens, out);
    mask_kernel<<<(NB * NT + 255) / 256, 256, 0, stream>>>(lens, out + 3 * MC);
}